// Round 3
// baseline (3713.507 us; speedup 1.0000x reference)
//
#include <hip/hip_runtime.h>
#include <cstdint>
#include <cstddef>

typedef unsigned short u16;
typedef unsigned long long u64;
typedef __attribute__((ext_vector_type(8))) short bf16x8;  // 8 x bf16 (4 VGPRs)
typedef __attribute__((ext_vector_type(4))) float f32x4;
typedef __attribute__((ext_vector_type(4))) unsigned short u16x4;

#define DEV __device__ __forceinline__

DEV float bf2f(u16 h) { union { unsigned int u; float f; } x; x.u = ((unsigned int)h) << 16; return x.f; }
DEV u16 f2bf(float f) {
    union { float f; unsigned int u; } x; x.f = f;
    unsigned int u = x.u;
    return (u16)((u + 0x7fffu + ((u >> 16) & 1u)) >> 16);   // RNE
}
// fast gate math: __expf + v_rcp_f32; rel err ~1e-6 << bf16 weight rounding
DEV float fsig(float x)  { float e = __expf(-x);      return __builtin_amdgcn_rcpf(1.0f + e); }
DEV float ftanh(float x) { float e = __expf(2.0f * x); return 1.0f - 2.0f * __builtin_amdgcn_rcpf(e + 1.0f); }
DEV f32x4 mfma16(bf16x8 a, bf16x8 b, f32x4 c) {
    return __builtin_amdgcn_mfma_f32_16x16x32_bf16(a, b, c, 0, 0, 0);
}

// B=256, T=256, E=128, H=128 (per direction), H2=256. ALL tensors fp32.
//
// r11: r10 post-mortem — setprio NULL => chain inflation is CU-level pipe
// sharing (LDS pipe conflicts 6x, MFMA pipe) + L2/MALL queueing, not issue
// arbitration. Fixes:
//  (1) XCD partition by blockIdx%8: chain blocks pin XCDs 0-3 (exactly fill
//      128 CUs x 2 blocks), GEMM blocks only ever land on XCDs 4-7. Chain
//      CUs host no GEMM waves. Correctness never depends on the mapping.
//  (2) Lean GEMMs: weights pre-converted to bf16 once; ln1(X1) precomputed
//      once into bf16 hi/lo planes IN PLACE over X1. H2 GEMM inner loop is
//      pure load->LDS->MFMA (no per-block LN/convert VALU). GEMM fits on
//      half the GPU under the chain time.
//  (3) s_sleep(1) throttle in the recur2 hot spin (MALL hot-spot relief).

union __align__(16) SMemU {
    struct { u16 As[64][40]; u16 Bs[64][40]; } g;   // GEMM staging (10240 B)
    struct { u16 Al[2][16][136]; } r1;              // recur1 h dbuf (8704 B)
    struct { u16 Al[16][264]; } r2;                 // recur2 h stage (8448 B)
};

// ---------------------------------------------------------------------------
// prep: fp32 -> bf16 weight conversion (one-time)
// ---------------------------------------------------------------------------
__global__ __launch_bounds__(256) void prep_w_kernel(
    const float* __restrict__ a, u16* __restrict__ o, int n)
{
    int i = blockIdx.x * 256 + threadIdx.x;
    if (i < n) o[i] = f2bf(a[i]);
}

// ---------------------------------------------------------------------------
// prep: ln1 over X1 rows, store bf16 hi/lo planes IN PLACE over the row.
// Row r (1KB): bytes [0,512) = H plane u16[256], [512,1024) = L plane.
// One wave per row: loads complete (waitcnt) before any store issues.
// ---------------------------------------------------------------------------
__global__ __launch_bounds__(256) void prep_x1_kernel(
    float* __restrict__ X, const float* __restrict__ gw, const float* __restrict__ bw)
{
    int row  = blockIdx.x * 4 + (threadIdx.x >> 6);
    int lane = threadIdx.x & 63;
    float* xr = X + (size_t)row * 256;
    f32x4 v = *(const f32x4*)(xr + lane * 4);
    float s = v[0] + v[1] + v[2] + v[3];
    #pragma unroll
    for (int mm = 1; mm < 64; mm <<= 1) s += __shfl_xor(s, mm, 64);
    float mu = s * (1.0f / 256.0f);
    f32x4 e = v - mu;
    float q = e[0]*e[0] + e[1]*e[1] + e[2]*e[2] + e[3]*e[3];
    #pragma unroll
    for (int mm = 1; mm < 64; mm <<= 1) q += __shfl_xor(q, mm, 64);
    float rs = rsqrtf(q * (1.0f / 256.0f) + 1e-5f);
    int c0 = lane * 4;
    u16x4 hv, lv;
    #pragma unroll
    for (int i = 0; i < 4; ++i) {
        float o = e[i] * rs * gw[c0 + i] + bw[c0 + i];
        u16 hh = f2bf(o);
        hv[i] = hh;
        lv[i] = f2bf(o - bf2f(hh));
    }
    u16* H = (u16*)xr;
    *(u16x4*)(H + lane * 4)       = hv;
    *(u16x4*)(H + 256 + lane * 4) = lv;
}

// ---------------------------------------------------------------------------
// xg GEMM body, first (bi) layer. A = embed fp32 (split on the fly),
// W = pre-converted bf16.
// ---------------------------------------------------------------------------
DEV void xg_fr_body(SMemU* smu, int bx, int by, int nby,
    const float* __restrict__ embed,
    const u16* __restrict__ Wf16, const float* __restrict__ bf_,
    const u16* __restrict__ Wr16, const float* __restrict__ br_,
    float* __restrict__ xgf, float* __restrict__ xgr, int t0f, int t0r)
{
    auto& As = smu->g.As;
    auto& Bs = smu->g.Bs;
    int tid = threadIdx.x;
    int half = nby >> 1;
    bool isR = by >= half;
    int m0 = (by - (isR ? half : 0)) * 64;
    const u16* W      = isR ? Wr16 : Wf16;
    const float* bias = isR ? br_ : bf_;
    float* out        = isR ? xgr : xgf;
    int tbase         = isR ? t0r : t0f;
    int n0 = bx * 64;

    int r  = tid >> 2;
    int kc = (tid & 3) * 8;
    int m  = m0 + r;
    int tl = m >> 8, bb = m & 255;
    const float* arow = embed + ((size_t)(bb * 256 + (tbase + tl)) * 128);
    const u16* brow = W + ((size_t)(n0 + r) * 128);

    f32x4 acc[4];
    #pragma unroll
    for (int i = 0; i < 4; ++i) acc[i] = (f32x4){0.f, 0.f, 0.f, 0.f};
    int lane = tid & 63, w = tid >> 6;
    int fr_ = lane & 15, kb0 = (lane >> 4) * 8;

    for (int kt = 0; kt < 8; ++kt) {
        int sc = (kt & 3) * 32 + kc;
        bool lo = kt >= 4;
        f32x4 va = *(const f32x4*)(arow + sc);
        f32x4 vb = *(const f32x4*)(arow + sc + 4);
        bf16x8 wv = *(const bf16x8*)(brow + sc);
        bf16x8 hv;
        #pragma unroll
        for (int i = 0; i < 8; ++i) {
            float v = (i < 4) ? va[i] : vb[i - 4];
            u16 hi = f2bf(v);
            hv[i] = (short)(lo ? f2bf(v - bf2f(hi)) : hi);
        }
        *(bf16x8*)&As[r][kc] = hv;
        *(bf16x8*)&Bs[r][kc] = wv;
        __syncthreads();
        bf16x8 bfrg = *(const bf16x8*)&Bs[w * 16 + fr_][kb0];
        #pragma unroll
        for (int mt = 0; mt < 4; ++mt) {
            bf16x8 afrg = *(const bf16x8*)&As[mt * 16 + fr_][kb0];
            acc[mt] = mfma16(afrg, bfrg, acc[mt]);
        }
        __syncthreads();
    }
    int col = n0 + w * 16 + fr_;
    float bvv = bias[col];
    int rq = (lane >> 4) * 4;
    #pragma unroll
    for (int mt = 0; mt < 4; ++mt)
        #pragma unroll
        for (int rr = 0; rr < 4; ++rr) {
            int mrow = m0 + mt * 16 + rq + rr;
            out[(size_t)mrow * 512 + col] = acc[mt][rr] + bvv;
        }
}

// ---------------------------------------------------------------------------
// LEAN layer-2 xg GEMM: A = pre-split bf16 hi/lo planes of ln1(X1) (in X1),
// W = pre-converted bf16. Inner loop: 16B loads -> LDS -> MFMA only.
// ---------------------------------------------------------------------------
DEV void xg_l16_body(SMemU* smu, int bx, int by,
    const u16* __restrict__ X1p, const u16* __restrict__ Wp,
    const float* __restrict__ bias, float* __restrict__ out, int t0)
{
    auto& As = smu->g.As;
    auto& Bs = smu->g.Bs;
    int tid = threadIdx.x;
    int m0 = by * 64, n0 = bx * 64;
    int r  = tid >> 2;
    int kc = (tid & 3) * 8;
    int m  = m0 + r;
    int tl = m >> 8, bb = m & 255;
    const u16* arow = X1p + ((size_t)((t0 + tl) * 256 + bb)) * 512;  // H[256] then L[256]
    const u16* brow = Wp + ((size_t)(n0 + r)) * 256;

    f32x4 acc[4];
    #pragma unroll
    for (int i = 0; i < 4; ++i) acc[i] = (f32x4){0.f, 0.f, 0.f, 0.f};
    int lane = tid & 63, w = tid >> 6;
    int fr_ = lane & 15, kb0 = (lane >> 4) * 8;

    for (int kt = 0; kt < 16; ++kt) {
        int sc = (kt & 7) * 32 + kc;
        bf16x8 hv = *(const bf16x8*)(arow + ((kt >= 8) ? 256 : 0) + sc);
        bf16x8 wv = *(const bf16x8*)(brow + sc);
        *(bf16x8*)&As[r][kc] = hv;
        *(bf16x8*)&Bs[r][kc] = wv;
        __syncthreads();
        bf16x8 bfrg = *(const bf16x8*)&Bs[w * 16 + fr_][kb0];
        #pragma unroll
        for (int mt = 0; mt < 4; ++mt) {
            bf16x8 afrg = *(const bf16x8*)&As[mt * 16 + fr_][kb0];
            acc[mt] = mfma16(afrg, bfrg, acc[mt]);
        }
        __syncthreads();
    }
    int col = n0 + w * 16 + fr_;
    float bvv = bias[col];
    int rq = (lane >> 4) * 4;
    #pragma unroll
    for (int mt = 0; mt < 4; ++mt)
        #pragma unroll
        for (int rr = 0; rr < 4; ++rr) {
            int mrow = m0 + mt * 16 + rq + rr;
            out[(size_t)mrow * 1024 + col] = acc[mt][rr] + bvv;
        }
}

// ---------------------------------------------------------------------------
// layer-3 xg GEMM: A = ln2( R + (H+L planes of ln1X1) ), W = bf16.
// ---------------------------------------------------------------------------
DEV void xg_ln3_body(SMemU* smu, int bx, int by,
    const u16* __restrict__ X1p, const float* __restrict__ Rc,
    const float* __restrict__ l2g, const float* __restrict__ l2b,
    const u16* __restrict__ Wp, const float* __restrict__ bias,
    float* __restrict__ out, int t0)
{
    auto& As = smu->g.As;
    auto& Bs = smu->g.Bs;
    int tid = threadIdx.x;
    int m0 = by * 64, n0 = bx * 64;
    int r  = tid >> 2;
    int kc = (tid & 3) * 8;
    int m  = m0 + r;
    int tl = m >> 8, bb = m & 255;
    const u16* a1 = X1p + ((size_t)((t0 + tl) * 256 + bb)) * 512;
    const float* a2 = Rc + ((size_t)(tl * 256 + bb)) * 256;
    const u16* brow = Wp + ((size_t)(n0 + r)) * 256;

    float xc[8][8];
    float s = 0.f;
    #pragma unroll
    for (int q = 0; q < 8; ++q) {
        int sc = q * 32 + kc;
        bf16x8 hx = *(const bf16x8*)(a1 + sc);
        bf16x8 lx = *(const bf16x8*)(a1 + 256 + sc);
        f32x4 u2 = *(const f32x4*)(a2 + sc);
        f32x4 v2 = *(const f32x4*)(a2 + sc + 4);
        #pragma unroll
        for (int i = 0; i < 8; ++i) {
            float rv = (i < 4) ? u2[i] : v2[i - 4];
            xc[q][i] = bf2f((u16)hx[i]) + bf2f((u16)lx[i]) + rv;
            s += xc[q][i];
        }
    }
    s += __shfl_xor(s, 1); s += __shfl_xor(s, 2);
    float mu = s * (1.0f / 256.0f);
    float q2 = 0.f;
    #pragma unroll
    for (int q = 0; q < 8; ++q)
        #pragma unroll
        for (int i = 0; i < 8; ++i) { float e = xc[q][i] - mu; q2 += e * e; }
    q2 += __shfl_xor(q2, 1); q2 += __shfl_xor(q2, 2);
    float rs = rsqrtf(q2 * (1.0f / 256.0f) + 1e-5f);
    #pragma unroll
    for (int q = 0; q < 8; ++q) {
        int sc = q * 32 + kc;
        f32x4 g1 = *(const f32x4*)(l2g + sc);
        f32x4 g2v = *(const f32x4*)(l2g + sc + 4);
        f32x4 h1 = *(const f32x4*)(l2b + sc);
        f32x4 h2 = *(const f32x4*)(l2b + sc + 4);
        #pragma unroll
        for (int i = 0; i < 4; ++i) {
            xc[q][i]     = (xc[q][i]     - mu) * rs * g1[i]  + h1[i];
            xc[q][4 + i] = (xc[q][4 + i] - mu) * rs * g2v[i] + h2[i];
        }
    }

    f32x4 acc[4];
    #pragma unroll
    for (int i = 0; i < 4; ++i) acc[i] = (f32x4){0.f, 0.f, 0.f, 0.f};
    int lane = tid & 63, w = tid >> 6;
    int fr_ = lane & 15, kb0 = (lane >> 4) * 8;

    #pragma unroll        // xc must be statically indexed (no scratch)
    for (int kt = 0; kt < 16; ++kt) {
        int q = kt & 7, sc = q * 32 + kc;
        bool lo = kt >= 8;
        bf16x8 wv = *(const bf16x8*)(brow + sc);
        bf16x8 hv;
        #pragma unroll
        for (int i = 0; i < 8; ++i) {
            float v = xc[q][i];
            u16 hi = f2bf(v);
            hv[i] = (short)(lo ? f2bf(v - bf2f(hi)) : hi);
        }
        *(bf16x8*)&As[r][kc] = hv;
        *(bf16x8*)&Bs[r][kc] = wv;
        __syncthreads();
        bf16x8 bfrg = *(const bf16x8*)&Bs[w * 16 + fr_][kb0];
        #pragma unroll
        for (int mt = 0; mt < 4; ++mt) {
            bf16x8 afrg = *(const bf16x8*)&As[mt * 16 + fr_][kb0];
            acc[mt] = mfma16(afrg, bfrg, acc[mt]);
        }
        __syncthreads();
    }
    int col = n0 + w * 16 + fr_;
    float bvv = bias[col];
    int rq = (lane >> 4) * 4;
    #pragma unroll
    for (int mt = 0; mt < 4; ++mt)
        #pragma unroll
        for (int rr = 0; rr < 4; ++rr) {
            int mrow = m0 + mt * 16 + rq + rr;
            out[(size_t)mrow * 1024 + col] = acc[mt][rr] + bvv;
        }
}

// ---------------------------------------------------------------------------
// Stage-1 recurrence body (H=128). One barrier per step, C-domain gate
// fusion, hi/lo h in LDS dbuf, next-step xg prefetch.
// ---------------------------------------------------------------------------
DEV void recur1_body(SMemU* smu, int bid,
    const float* __restrict__ xgf, const float* __restrict__ xgr,
    const float* __restrict__ whhf, const float* __restrict__ whhr,
    float* __restrict__ cbf, float* __restrict__ cbr,
    float* __restrict__ hpf, float* __restrict__ hpr,
    float* __restrict__ xout, int s0, int s1)
{
    __builtin_amdgcn_s_setprio(1);
    constexpr int K = 128, N4 = 512;
    auto& Al = smu->r1.Al;

    int tid = threadIdx.x, lane = tid & 63, w = tid >> 6;
    int fr_ = lane & 15, quad = lane >> 4, kb0 = quad * 8;
    int dir = bid >> 5, gidx = bid & 31;
    const float* xg  = dir ? xgr  : xgf;
    const float* whh = dir ? whhr : whhf;
    float* cb = dir ? cbr : cbf;
    float* hp = dir ? hpr : hpf;
    int coloff = dir ? 128 : 0;

    bf16x8 bf[4][2][4];
    #pragma unroll
    for (int g = 0; g < 4; ++g)
        #pragma unroll
        for (int u = 0; u < 2; ++u) {
            const float* src = whh + (size_t)(g * K + w * 32 + u * 16 + fr_) * K;
            #pragma unroll
            for (int kt = 0; kt < 4; ++kt) {
                f32x4 a = *(const f32x4*)(src + kt * 32 + kb0);
                f32x4 b = *(const f32x4*)(src + kt * 32 + kb0 + 4);
                bf16x8 wv;
                #pragma unroll
                for (int i = 0; i < 8; ++i) wv[i] = (short)f2bf((i < 4) ? a[i] : b[i - 4]);
                bf[g][u][kt] = wv;
            }
        }

    int uq = quad >> 1, qrow = quad & 1;
    int colw = w * 32 + uq * 16 + fr_;        // 0..127
    int b0 = gidx * 8;
    float c[4];
    #pragma unroll
    for (int rr = 0; rr < 4; ++rr)
        c[rr] = (s0 > 0) ? cb[(size_t)(b0 + qrow * 4 + rr) * K + colw] : 0.f;

    if (s0 > 0) {   // preload h (fp32) into Al[s0&1] hi/lo
        for (int idx = tid; idx < 8 * K; idx += 256) {
            int sa = idx >> 7, k = idx & 127;
            float v = hp[(size_t)(b0 + sa) * K + k];
            u16 hh = f2bf(v);
            Al[s0 & 1][sa][k] = hh;
            Al[s0 & 1][8 + sa][k] = f2bf(v - bf2f(hh));
        }
    }
    __syncthreads();

    // prefetch xg for the first step
    float xv[4][4];
    {
        int xrow = dir ? (s1 - 1 - s0) : 0;
        #pragma unroll
        for (int rr = 0; rr < 4; ++rr) {
            const float* xp = xg + ((size_t)(xrow * 256 + b0 + qrow * 4 + rr)) * N4 + colw;
            #pragma unroll
            for (int g = 0; g < 4; ++g) xv[rr][g] = xp[g * K];
        }
    }

    for (int t = s0; t < s1; ++t) {
        float xn[4][4];
        {
            int tn = (t + 1 < s1) ? (t + 1) : t;
            int xrow = dir ? (s1 - 1 - tn) : (tn - s0);
            #pragma unroll
            for (int rr = 0; rr < 4; ++rr) {
                const float* xp = xg + ((size_t)(xrow * 256 + b0 + qrow * 4 + rr)) * N4 + colw;
                #pragma unroll
                for (int g = 0; g < 4; ++g) xn[rr][g] = xp[g * K];
            }
        }
        f32x4 acc[4][2];
        if (t > 0) {
            #pragma unroll
            for (int g = 0; g < 4; ++g)
                #pragma unroll
                for (int u = 0; u < 2; ++u) acc[g][u] = (f32x4){0.f, 0.f, 0.f, 0.f};
            #pragma unroll
            for (int kt = 0; kt < 4; ++kt) {
                bf16x8 a = *(const bf16x8*)&Al[t & 1][fr_][kt * 32 + kb0];
                #pragma unroll
                for (int g = 0; g < 4; ++g)
                    #pragma unroll
                    for (int u = 0; u < 2; ++u) acc[g][u] = mfma16(a, bf[g][u][kt], acc[g][u]);
            }
            // combine hi (quads 0,1) + lo (quads 2,3): UNIFORM indices only
            #pragma unroll
            for (int g = 0; g < 4; ++g)
                #pragma unroll
                for (int u = 0; u < 2; ++u)
                    #pragma unroll
                    for (int rr = 0; rr < 4; ++rr)
                        acc[g][u][rr] += __shfl_xor(acc[g][u][rr], 32);
        }
        int tt = dir ? (255 - t) : t;
        #pragma unroll
        for (int rr = 0; rr < 4; ++rr) {
            int s = qrow * 4 + rr;
            float gg[4];
            #pragma unroll
            for (int g = 0; g < 4; ++g) {
                float pv = (t > 0) ? (uq ? acc[g][1][rr] : acc[g][0][rr]) : 0.f;
                gg[g] = xv[rr][g] + pv;
            }
            c[rr] = fsig(gg[1]) * c[rr] + fsig(gg[0]) * ftanh(gg[2]);
            float h = fsig(gg[3]) * ftanh(c[rr]);
            u16 hh = f2bf(h);
            Al[(t + 1) & 1][s][colw] = hh;
            Al[(t + 1) & 1][8 + s][colw] = f2bf(h - bf2f(hh));
            xout[((size_t)tt * 256 + b0 + s) * 256 + coloff + colw] = h;
            if (t == s1 - 1) hp[(size_t)(b0 + s) * K + colw] = h;
        }
        __syncthreads();
        #pragma unroll
        for (int rr = 0; rr < 4; ++rr)
            #pragma unroll
            for (int g = 0; g < 4; ++g) xv[rr][g] = xn[rr][g];
    }
    #pragma unroll
    for (int rr = 0; rr < 4; ++rr)
        cb[(size_t)(b0 + qrow * 4 + rr) * K + colw] = c[rr];
}

// ---------------------------------------------------------------------------
// H2 recurrence body (K=256). 64-bit tagged agent-atomic h exchange, one
// barrier/step, next-step xg prefetch, s_sleep-throttled spin.
// OUTY 0: write h to chunk-local buffer. OUTY 1: write y at t==lastidx[b].
// ---------------------------------------------------------------------------
template<int OUTY>
DEV void recur2_body(SMemU* smu, int bid,
    const float* __restrict__ xg, const float* __restrict__ whh,
    float* __restrict__ cb, u64* hb,
    float* __restrict__ xoutc, float* __restrict__ yout,
    const int* __restrict__ lastidx,
    const float* __restrict__ bng, const float* __restrict__ bnb,
    int s0, int s1)
{
    __builtin_amdgcn_s_setprio(1);
    constexpr int K = 256, MB = 8, N4 = 1024;
    constexpr int CNT = MB * K / 256;   // 8 poll words per thread
    auto& Al = smu->r2.Al;

    int tid = threadIdx.x, lane = tid & 63, w = tid >> 6;
    int fr_ = lane & 15, quad = lane >> 4, kb0 = quad * 8;
    int group = bid >> 2, cw = bid & 3;
    u64* hbg = hb + (size_t)group * (2 * MB * K);
    int col = cw * 64 + w * 16 + fr_;         // 0..255

    bf16x8 bf[4][8];
    #pragma unroll
    for (int g = 0; g < 4; ++g) {
        const float* src = whh + (size_t)(g * 256 + col) * K;
        #pragma unroll
        for (int kt = 0; kt < 8; ++kt) {
            f32x4 a = *(const f32x4*)(src + kt * 32 + kb0);
            f32x4 b = *(const f32x4*)(src + kt * 32 + kb0 + 4);
            bf16x8 wv;
            #pragma unroll
            for (int i = 0; i < 8; ++i) wv[i] = (short)f2bf((i < 4) ? a[i] : b[i - 4]);
            bf[g][kt] = wv;
        }
    }

    int qrow = quad & 1, rhalf = quad >> 1;
    int sp[2], bs[2]; float c[2];
    #pragma unroll
    for (int j = 0; j < 2; ++j) {
        sp[j] = qrow * 4 + rhalf * 2 + j;     // sample-local 0..7
        bs[j] = group * 8 + sp[j];
        c[j] = (s0 > 0) ? cb[(size_t)bs[j] * K + col] : 0.f;
    }
    int lastb[2] = { -1, -1 };
    float bngv = 0.f, bnbv = 0.f;
    if (OUTY) {
        bool is64 = (lastidx[1] | lastidx[3] | lastidx[5] | lastidx[7] |
                     lastidx[9] | lastidx[11] | lastidx[13] | lastidx[15]) == 0;
        lastb[0] = is64 ? lastidx[2 * bs[0]] : lastidx[bs[0]];
        lastb[1] = is64 ? lastidx[2 * bs[1]] : lastidx[bs[1]];
        bngv = bng[col] * rsqrtf(1.0f + 1e-5f);
        bnbv = bnb[col];
    }

    // prefetch xg for the first step
    float xv[2][4];
    #pragma unroll
    for (int j = 0; j < 2; ++j) {
        const float* xp = xg + ((size_t)bs[j]) * N4 + col;
        #pragma unroll
        for (int g = 0; g < 4; ++g) xv[j][g] = xp[g * 256];
    }

    for (int t = s0; t < s1; ++t) {
        // issue next-step xg loads early
        float xn[2][4];
        {
            int tn = (t + 1 < s1) ? (t + 1) : t;
            int xr = tn - s0;
            #pragma unroll
            for (int j = 0; j < 2; ++j) {
                const float* xp = xg + ((size_t)(xr * 256 + bs[j])) * N4 + col;
                #pragma unroll
                for (int g = 0; g < 4; ++g) xn[j][g] = xp[g * 256];
            }
        }
        f32x4 acc[4];
        if (t > 0) {
            u64* hsrc = hbg + (size_t)(t & 1) * (MB * K);
            u64 v[CNT];
            #pragma unroll
            for (int i = 0; i < CNT; ++i)
                v[i] = __hip_atomic_load(hsrc + tid + i * 256,
                                         __ATOMIC_RELAXED, __HIP_MEMORY_SCOPE_AGENT);
            for (;;) {
                bool ok = true;
                #pragma unroll
                for (int i = 0; i < CNT; ++i)
                    if ((unsigned int)(v[i] >> 32) != (unsigned int)t) ok = false;
                if (ok) break;
                __builtin_amdgcn_s_sleep(1);   // throttle spin (MALL hot-spot)
                #pragma unroll
                for (int i = 0; i < CNT; ++i)
                    if ((unsigned int)(v[i] >> 32) != (unsigned int)t)
                        v[i] = __hip_atomic_load(hsrc + tid + i * 256,
                                                 __ATOMIC_RELAXED, __HIP_MEMORY_SCOPE_AGENT);
            }
            // stage: word idx = tid + i*256 -> sample i, col tid
            #pragma unroll
            for (int i = 0; i < CNT; ++i) {
                unsigned int d = (unsigned int)v[i];
                Al[i][tid]     = (u16)(d & 0xffffu);
                Al[8 + i][tid] = (u16)(d >> 16);
            }
            __syncthreads();
            #pragma unroll
            for (int g = 0; g < 4; ++g) acc[g] = (f32x4){0.f, 0.f, 0.f, 0.f};
            #pragma unroll
            for (int kt = 0; kt < 8; ++kt) {
                bf16x8 a = *(const bf16x8*)&Al[fr_][kt * 32 + kb0];
                #pragma unroll
                for (int g = 0; g < 4; ++g) acc[g] = mfma16(a, bf[g][kt], acc[g]);
            }
            // combine hi (quads 0,1) + lo (quads 2,3): UNIFORM indices only
            #pragma unroll
            for (int g = 0; g < 4; ++g)
                #pragma unroll
                for (int rr = 0; rr < 4; ++rr)
                    acc[g][rr] += __shfl_xor(acc[g][rr], 32);
        }
        #pragma unroll
        for (int j = 0; j < 2; ++j) {
            float gg[4];
            #pragma unroll
            for (int g = 0; g < 4; ++g) {
                float pv = (t > 0) ? (rhalf ? acc[g][2 + j] : acc[g][j]) : 0.f;
                gg[g] = xv[j][g] + pv;
            }
            c[j] = fsig(gg[1]) * c[j] + fsig(gg[0]) * ftanh(gg[2]);
            float h = fsig(gg[3]) * ftanh(c[j]);
            u16 hh = f2bf(h);
            u16 hl = f2bf(h - bf2f(hh));
            u64 word = (u64)((unsigned int)hh | ((unsigned int)hl << 16))
                     | ((u64)(unsigned int)(t + 1) << 32);
            __hip_atomic_store(hbg + (size_t)((t + 1) & 1) * (MB * K) + (size_t)sp[j] * K + col,
                               word, __ATOMIC_RELAXED, __HIP_MEMORY_SCOPE_AGENT);
            if (OUTY == 0) {
                xoutc[((size_t)(t - s0) * 256 + bs[j]) * 256 + col] = h;
            } else if (t == lastb[j]) {
                float y = h * bngv + bnbv;
                y = y > 0.f ? y : 0.f;
                yout[(size_t)bs[j] * 256 + col] = y;
            }
        }
        #pragma unroll
        for (int j = 0; j < 2; ++j)
            #pragma unroll
            for (int g = 0; g < 4; ++g) xv[j][g] = xn[j][g];
    }
    #pragma unroll
    for (int j = 0; j < 2; ++j) cb[(size_t)bs[j] * K + col] = c[j];
}

// ---------------------------------------------------------------------------
// Fused stage-1 launch, XCD-partitioned:
//  chain (recur1, 64 blocks): b<512 && b%8==0  -> pins XCD0
//  GEMM  (xg_fr, 2048 blocks): everything else -> XCDs 1-7
// ---------------------------------------------------------------------------
__global__ __launch_bounds__(256) void fused1_kernel(
    const float* __restrict__ embed,
    const u16* __restrict__ Wf16, const float* __restrict__ bfb,
    const u16* __restrict__ Wr16, const float* __restrict__ brb,
    float* __restrict__ xgfw, float* __restrict__ xgrw, int t0f, int t0r, int gon,
    const float* __restrict__ xgfr, const float* __restrict__ xgrr,
    const float* __restrict__ whhf, const float* __restrict__ whhr,
    float* __restrict__ cbf, float* __restrict__ cbr,
    float* __restrict__ hpf, float* __restrict__ hpr,
    float* __restrict__ X1, int s0, int s1, int ron)
{
    __shared__ SMemU sm;
    int b = blockIdx.x;
    if (b < 512 && (b & 7) == 0) {
        if (ron)
            recur1_body(&sm, b >> 3, xgfr, xgrr, whhf, whhr, cbf, cbr, hpf, hpr, X1, s0, s1);
    } else {
        if (gon) {
            int gidx = (b < 512) ? ((b >> 3) * 7 + (b & 7) - 1) : (448 + b - 512);
            xg_fr_body(&sm, gidx & 7, gidx >> 3, 256, embed, Wf16, bfb, Wr16, brb,
                       xgfw, xgrw, t0f, t0r);
        }
    }
}

// ---------------------------------------------------------------------------
// Fused stage-2/3 slot launch, XCD-partitioned:
//  chain (256 blocks): b<512 && b%8<4 -> pins XCDs 0-3 (128 CUs x 2 exactly)
//    cid<128: recur2 layer-1 (OUTY=0) chunk i   -> R[i&1]
//    cid>=128: recur2 layer-2 (OUTY=1) chunk i-2 -> y
//  GEMM (2048 blocks): the rest -> XCDs 4-7
//    gidx<1024:  lean xg layer-1 chunk i+1      -> G2[(i+1)&1]
//    gidx>=1024: xg layer-2 (+res+ln2) chunk i-1 -> G3[(i-1)&1]
// ---------------------------------------------------------------------------
__global__ __launch_bounds__(256) void fused2_kernel(
    const float* __restrict__ xg2, const float* __restrict__ w1hh,
    float* __restrict__ cb1, u64* hb1, float* __restrict__ Rw,
    int s2a, int s2b, int s2on,
    const float* __restrict__ xg3, const float* __restrict__ w2hh,
    float* __restrict__ cb2, u64* hb2, float* __restrict__ yout,
    const int* __restrict__ lastidx, const float* __restrict__ bng,
    const float* __restrict__ bnb, int s3a, int s3b, int s3on,
    const u16* __restrict__ X1p, const u16* __restrict__ w1p,
    const float* __restrict__ b1, float* __restrict__ G2w, int g2t0, int g2on,
    const float* __restrict__ Rr, const float* __restrict__ ln2g,
    const float* __restrict__ ln2b, const u16* __restrict__ w2p,
    const float* __restrict__ b2v, float* __restrict__ G3w, int g3t0, int g3on)
{
    __shared__ SMemU sm;
    int b = blockIdx.x;
    if (b < 512 && (b & 7) < 4) {
        int cid = (b >> 3) * 4 + (b & 7);          // 0..255
        if (cid < 128) {
            if (s2on)
                recur2_body<0>(&sm, cid, xg2, w1hh, cb1, hb1, Rw,
                               nullptr, nullptr, nullptr, nullptr, s2a, s2b);
        } else {
            if (s3on)
                recur2_body<1>(&sm, cid - 128, xg3, w2hh, cb2, hb2,
                               nullptr, yout, lastidx, bng, bnb, s3a, s3b);
        }
    } else {
        int gidx = (b < 512) ? ((b >> 3) * 4 + (b & 7) - 4) : (256 + b - 512);  // 0..2047
        if (gidx < 1024) {
            if (g2on)
                xg_l16_body(&sm, gidx & 15, gidx >> 4, X1p, w1p, b1, G2w, g2t0);
        } else {
            if (g3on) {
                int i = gidx - 1024;
                xg_ln3_body(&sm, i & 15, i >> 4, X1p, Rr, ln2g, ln2b, w2p, b2v, G3w, g3t0);
            }
        }
    }
}

// standalone lean layer-2 xg GEMM for chunk 0 (after prep_x1)
__global__ __launch_bounds__(256) void xg2_kernel(
    const u16* __restrict__ X1p, const u16* __restrict__ Wp,
    const float* __restrict__ bias, float* __restrict__ out, int t0)
{
    __shared__ SMemU sm;
    xg_l16_body(&sm, blockIdx.x, blockIdx.y, X1p, Wp, bias, out, t0);
}

// ---------------------------------------------------------------------------
// Launch
// ---------------------------------------------------------------------------
extern "C" void kernel_launch(void* const* d_in, const int* in_sizes, int n_in,
                              void* d_out, int out_size, void* d_ws, size_t ws_size,
                              hipStream_t stream)
{
    (void)in_sizes; (void)n_in; (void)out_size; (void)ws_size;
    const float* embed = (const float*)d_in[0];
    const int* lastidx = (const int*)d_in[1];
    const float* Wih_f = (const float*)d_in[2];
    const float* Whh_f = (const float*)d_in[3];
    const float* b_f   = (const float*)d_in[4];
    const float* Wih_r = (const float*)d_in[5];
    const float* Whh_r = (const float*)d_in[6];
    const float* b_r   = (const float*)d_in[7];
    const float* ln1g  = (const float*)d_in[8];
    const float* ln1b  = (const float*)d_in[9];
    const float* W1ih  = (const float*)d_in[10];
    const float* W1hh  = (const float*)d_in[11];
    const float* b1    = (const float*)d_in[12];
    const float* ln2g  = (const float*)d_in[13];
    const float* ln2b  = (const float*)d_in[14];
    const float* W2ih  = (const float*)d_in[15];
    const float* W2hh  = (const float*)d_in[16];
    const float* b2    = (const float*)d_in[17];
    const float* bng   = (const float*)d_in[18];
    const float* bnb   = (const float*)d_in[19];

    const size_t MiB = 1024 * 1024;
    char* ws = (char*)d_ws;
    float* G2[2] = { (float*)ws,               (float*)(ws + 16 * MiB) };
    float* G3[2] = { (float*)(ws + 32 * MiB),  (float*)(ws + 48 * MiB) };
    float* X1    =   (float*)(ws + 64 * MiB);   // 64 MiB; ln1 bf16 planes in place after prep
    float* R[2]  = { (float*)(ws + 128 * MiB), (float*)(ws + 132 * MiB) };  // 4 MiB each
    char* p = ws + 136 * MiB;
    u64* hb1 = (u64*)p;                         p += 1024 * 1024;
    u64* hb2 = (u64*)p;                         p += 1024 * 1024;
    float* cbf = (float*)p;                     p += 128 * 1024;
    float* cbr = (float*)p;                     p += 128 * 1024;
    float* cb1 = (float*)p;                     p += 256 * 1024;
    float* cb2 = (float*)p;                     p += 256 * 1024;
    float* hpf = (float*)p;                     p += 128 * 1024;
    float* hpr = (float*)p;                     p += 128 * 1024;
    u16* w1p   = (u16*)p;                       p += 512 * 1024;   // W1ih bf16 [1024][256]
    u16* w2p   = (u16*)p;                       p += 512 * 1024;   // W2ih bf16
    u16* wfp   = (u16*)p;                       p += 128 * 1024;   // Wih_f bf16 [512][128]
    u16* wrp   = (u16*)p;                       // Wih_r bf16

    const int CH1 = 32, n1 = 8;    // stage-1 chunking
    const int CH  = 16, n2 = 16;   // stage-2/3 chunking

    // one-time weight conversions
    prep_w_kernel<<<1024, 256, 0, stream>>>(W1ih, w1p, 262144);
    prep_w_kernel<<<1024, 256, 0, stream>>>(W2ih, w2p, 262144);
    prep_w_kernel<<<256, 256, 0, stream>>>(Wih_f, wfp, 65536);
    prep_w_kernel<<<256, 256, 0, stream>>>(Wih_r, wrp, 65536);

    // stage 1: bidirectional H=128 LSTM -> X1 (raw concat)
    for (int i = 0; i <= n1; ++i) {
        int gon = (i < n1), ron = (i >= 1);
        float* wf = (i & 1) ? G3[0] : G2[0];
        float* wr = (i & 1) ? G3[1] : G2[1];
        const float* rf = ((i - 1) & 1) ? G3[0] : G2[0];
        const float* rr_ = ((i - 1) & 1) ? G3[1] : G2[1];
        fused1_kernel<<<2112, 256, 0, stream>>>(
            embed, wfp, b_f, wrp, b_r, wf, wr, CH1 * i, 256 - CH1 * (i + 1), gon,
            rf, rr_, Whh_f, Whh_r, cbf, cbr, hpf, hpr, X1, CH1 * (i - 1), CH1 * i, ron);
    }

    // ln1 + bf16 hi/lo split, in place over X1
    prep_x1_kernel<<<16384, 256, 0, stream>>>(X1, ln1g, ln1b);
    const u16* X1p = (const u16*)X1;

    // stages 2+3, deep pipeline
    xg2_kernel<<<dim3(16, CH * 4), 256, 0, stream>>>(X1p, w1p, b1, G2[0], 0);
    for (int i = 0; i <= n2 + 1; ++i) {
        int s2on = (i < n2), s3on = (i >= 2);
        int g2on = (i + 1 < n2), g3on = (i >= 1 && i <= n2);
        fused2_kernel<<<2304, 256, 0, stream>>>(
            G2[i & 1], W1hh, cb1, hb1, R[i & 1], CH * i, CH * (i + 1), s2on,
            G3[(i - 2) & 1], W2hh, cb2, hb2, (float*)d_out, lastidx, bng, bnb,
            CH * (i - 2), CH * (i - 1), s3on,
            X1p, w1p, b1, G2[(i + 1) & 1], CH * (i + 1), g2on,
            R[(i - 1) & 1], ln2g, ln2b, w2p, b2, G3[(i - 1) & 1], CH * (i - 1), g3on);
    }
}

// Round 4
// 2402.821 us; speedup vs baseline: 1.5455x; 1.5455x over previous
//
#include <hip/hip_runtime.h>
#include <cstdint>
#include <cstddef>

typedef unsigned short u16;
typedef unsigned long long u64;
typedef __attribute__((ext_vector_type(8))) short bf16x8;  // 8 x bf16 (4 VGPRs)
typedef __attribute__((ext_vector_type(4))) float f32x4;
typedef __attribute__((ext_vector_type(4))) unsigned short u16x4;

#define DEV __device__ __forceinline__

DEV float bf2f(u16 h) { union { unsigned int u; float f; } x; x.u = ((unsigned int)h) << 16; return x.f; }
DEV u16 f2bf(float f) {
    union { float f; unsigned int u; } x; x.f = f;
    unsigned int u = x.u;
    return (u16)((u + 0x7fffu + ((u >> 16) & 1u)) >> 16);   // RNE
}
// fast gate math: __expf + v_rcp_f32; rel err ~1e-6 << bf16 weight rounding
DEV float fsig(float x)  { float e = __expf(-x);      return __builtin_amdgcn_rcpf(1.0f + e); }
DEV float ftanh(float x) { float e = __expf(2.0f * x); return 1.0f - 2.0f * __builtin_amdgcn_rcpf(e + 1.0f); }
DEV f32x4 mfma16(bf16x8 a, bf16x8 b, f32x4 c) {
    return __builtin_amdgcn_mfma_f32_16x16x32_bf16(a, b, c, 0, 0, 0);
}

// B=256, T=256, E=128, H=128 (per direction), H2=256. ALL tensors fp32.
//
// r12: r3 post-mortem — the XCD-partition remap caused the fused1 regression
// (30 -> 166 us) and was null on fused2 => chain inflation is CONTINUOUS GEMM
// CHURN (2048 fat blocks ~ 96 us of machine time fills the whole launch), not
// CU co-residency per se and not issue arbitration (r2). This round:
// r1's proven block layout (chain = lowest ids, natural order) + r3's proven
// lean GEMM machinery (bf16 weights pre-converted; ln1 pre-applied into bf16
// hi/lo planes in place over X1; pure load->LDS->MFMA inner loops). Lean
// blocks cut churn to ~40 us/launch so the chain runs near-standalone speed
// for most of each slot.

union __align__(16) SMemU {
    struct { u16 As[64][40]; u16 Bs[64][40]; } g;   // GEMM staging (10240 B)
    struct { u16 Al[2][16][136]; } r1;              // recur1 h dbuf (8704 B)
    struct { u16 Al[16][264]; } r2;                 // recur2 h stage (8448 B)
};

// ---------------------------------------------------------------------------
// prep: fp32 -> bf16 weight conversion (one-time)
// ---------------------------------------------------------------------------
__global__ __launch_bounds__(256) void prep_w_kernel(
    const float* __restrict__ a, u16* __restrict__ o, int n)
{
    int i = blockIdx.x * 256 + threadIdx.x;
    if (i < n) o[i] = f2bf(a[i]);
}

// ---------------------------------------------------------------------------
// prep: ln1 over X1 rows, store bf16 hi/lo planes IN PLACE over the row.
// Row r (1KB): bytes [0,512) = H plane u16[256], [512,1024) = L plane.
// One wave per row: loads complete (waitcnt) before any store issues.
// ---------------------------------------------------------------------------
__global__ __launch_bounds__(256) void prep_x1_kernel(
    float* __restrict__ X, const float* __restrict__ gw, const float* __restrict__ bw)
{
    int row  = blockIdx.x * 4 + (threadIdx.x >> 6);
    int lane = threadIdx.x & 63;
    float* xr = X + (size_t)row * 256;
    f32x4 v = *(const f32x4*)(xr + lane * 4);
    float s = v[0] + v[1] + v[2] + v[3];
    #pragma unroll
    for (int mm = 1; mm < 64; mm <<= 1) s += __shfl_xor(s, mm, 64);
    float mu = s * (1.0f / 256.0f);
    f32x4 e = v - mu;
    float q = e[0]*e[0] + e[1]*e[1] + e[2]*e[2] + e[3]*e[3];
    #pragma unroll
    for (int mm = 1; mm < 64; mm <<= 1) q += __shfl_xor(q, mm, 64);
    float rs = rsqrtf(q * (1.0f / 256.0f) + 1e-5f);
    int c0 = lane * 4;
    u16x4 hv, lv;
    #pragma unroll
    for (int i = 0; i < 4; ++i) {
        float o = e[i] * rs * gw[c0 + i] + bw[c0 + i];
        u16 hh = f2bf(o);
        hv[i] = hh;
        lv[i] = f2bf(o - bf2f(hh));
    }
    u16* H = (u16*)xr;
    *(u16x4*)(H + lane * 4)       = hv;
    *(u16x4*)(H + 256 + lane * 4) = lv;
}

// ---------------------------------------------------------------------------
// xg GEMM body, first (bi) layer. A = embed fp32 (split on the fly),
// W = pre-converted bf16.
// ---------------------------------------------------------------------------
DEV void xg_fr_body(SMemU* smu, int bx, int by, int nby,
    const float* __restrict__ embed,
    const u16* __restrict__ Wf16, const float* __restrict__ bf_,
    const u16* __restrict__ Wr16, const float* __restrict__ br_,
    float* __restrict__ xgf, float* __restrict__ xgr, int t0f, int t0r)
{
    auto& As = smu->g.As;
    auto& Bs = smu->g.Bs;
    int tid = threadIdx.x;
    int half = nby >> 1;
    bool isR = by >= half;
    int m0 = (by - (isR ? half : 0)) * 64;
    const u16* W      = isR ? Wr16 : Wf16;
    const float* bias = isR ? br_ : bf_;
    float* out        = isR ? xgr : xgf;
    int tbase         = isR ? t0r : t0f;
    int n0 = bx * 64;

    int r  = tid >> 2;
    int kc = (tid & 3) * 8;
    int m  = m0 + r;
    int tl = m >> 8, bb = m & 255;
    const float* arow = embed + ((size_t)(bb * 256 + (tbase + tl)) * 128);
    const u16* brow = W + ((size_t)(n0 + r) * 128);

    f32x4 acc[4];
    #pragma unroll
    for (int i = 0; i < 4; ++i) acc[i] = (f32x4){0.f, 0.f, 0.f, 0.f};
    int lane = tid & 63, w = tid >> 6;
    int fr_ = lane & 15, kb0 = (lane >> 4) * 8;

    for (int kt = 0; kt < 8; ++kt) {
        int sc = (kt & 3) * 32 + kc;
        bool lo = kt >= 4;
        f32x4 va = *(const f32x4*)(arow + sc);
        f32x4 vb = *(const f32x4*)(arow + sc + 4);
        bf16x8 wv = *(const bf16x8*)(brow + sc);
        bf16x8 hv;
        #pragma unroll
        for (int i = 0; i < 8; ++i) {
            float v = (i < 4) ? va[i] : vb[i - 4];
            u16 hi = f2bf(v);
            hv[i] = (short)(lo ? f2bf(v - bf2f(hi)) : hi);
        }
        *(bf16x8*)&As[r][kc] = hv;
        *(bf16x8*)&Bs[r][kc] = wv;
        __syncthreads();
        bf16x8 bfrg = *(const bf16x8*)&Bs[w * 16 + fr_][kb0];
        #pragma unroll
        for (int mt = 0; mt < 4; ++mt) {
            bf16x8 afrg = *(const bf16x8*)&As[mt * 16 + fr_][kb0];
            acc[mt] = mfma16(afrg, bfrg, acc[mt]);
        }
        __syncthreads();
    }
    int col = n0 + w * 16 + fr_;
    float bvv = bias[col];
    int rq = (lane >> 4) * 4;
    #pragma unroll
    for (int mt = 0; mt < 4; ++mt)
        #pragma unroll
        for (int rr = 0; rr < 4; ++rr) {
            int mrow = m0 + mt * 16 + rq + rr;
            out[(size_t)mrow * 512 + col] = acc[mt][rr] + bvv;
        }
}

// ---------------------------------------------------------------------------
// LEAN layer-2 xg GEMM: A = pre-split bf16 hi/lo planes of ln1(X1) (in X1),
// W = pre-converted bf16. Inner loop: 16B loads -> LDS -> MFMA only.
// ---------------------------------------------------------------------------
DEV void xg_l16_body(SMemU* smu, int bx, int by,
    const u16* __restrict__ X1p, const u16* __restrict__ Wp,
    const float* __restrict__ bias, float* __restrict__ out, int t0)
{
    auto& As = smu->g.As;
    auto& Bs = smu->g.Bs;
    int tid = threadIdx.x;
    int m0 = by * 64, n0 = bx * 64;
    int r  = tid >> 2;
    int kc = (tid & 3) * 8;
    int m  = m0 + r;
    int tl = m >> 8, bb = m & 255;
    const u16* arow = X1p + ((size_t)((t0 + tl) * 256 + bb)) * 512;  // H[256] then L[256]
    const u16* brow = Wp + ((size_t)(n0 + r)) * 256;

    f32x4 acc[4];
    #pragma unroll
    for (int i = 0; i < 4; ++i) acc[i] = (f32x4){0.f, 0.f, 0.f, 0.f};
    int lane = tid & 63, w = tid >> 6;
    int fr_ = lane & 15, kb0 = (lane >> 4) * 8;

    for (int kt = 0; kt < 16; ++kt) {
        int sc = (kt & 7) * 32 + kc;
        bf16x8 hv = *(const bf16x8*)(arow + ((kt >= 8) ? 256 : 0) + sc);
        bf16x8 wv = *(const bf16x8*)(brow + sc);
        *(bf16x8*)&As[r][kc] = hv;
        *(bf16x8*)&Bs[r][kc] = wv;
        __syncthreads();
        bf16x8 bfrg = *(const bf16x8*)&Bs[w * 16 + fr_][kb0];
        #pragma unroll
        for (int mt = 0; mt < 4; ++mt) {
            bf16x8 afrg = *(const bf16x8*)&As[mt * 16 + fr_][kb0];
            acc[mt] = mfma16(afrg, bfrg, acc[mt]);
        }
        __syncthreads();
    }
    int col = n0 + w * 16 + fr_;
    float bvv = bias[col];
    int rq = (lane >> 4) * 4;
    #pragma unroll
    for (int mt = 0; mt < 4; ++mt)
        #pragma unroll
        for (int rr = 0; rr < 4; ++rr) {
            int mrow = m0 + mt * 16 + rq + rr;
            out[(size_t)mrow * 1024 + col] = acc[mt][rr] + bvv;
        }
}

// ---------------------------------------------------------------------------
// layer-3 xg GEMM: A = ln2( R + (H+L planes of ln1X1) ), W = bf16.
// ---------------------------------------------------------------------------
DEV void xg_ln3_body(SMemU* smu, int bx, int by,
    const u16* __restrict__ X1p, const float* __restrict__ Rc,
    const float* __restrict__ l2g, const float* __restrict__ l2b,
    const u16* __restrict__ Wp, const float* __restrict__ bias,
    float* __restrict__ out, int t0)
{
    auto& As = smu->g.As;
    auto& Bs = smu->g.Bs;
    int tid = threadIdx.x;
    int m0 = by * 64, n0 = bx * 64;
    int r  = tid >> 2;
    int kc = (tid & 3) * 8;
    int m  = m0 + r;
    int tl = m >> 8, bb = m & 255;
    const u16* a1 = X1p + ((size_t)((t0 + tl) * 256 + bb)) * 512;
    const float* a2 = Rc + ((size_t)(tl * 256 + bb)) * 256;
    const u16* brow = Wp + ((size_t)(n0 + r)) * 256;

    float xc[8][8];
    float s = 0.f;
    #pragma unroll
    for (int q = 0; q < 8; ++q) {
        int sc = q * 32 + kc;
        bf16x8 hx = *(const bf16x8*)(a1 + sc);
        bf16x8 lx = *(const bf16x8*)(a1 + 256 + sc);
        f32x4 u2 = *(const f32x4*)(a2 + sc);
        f32x4 v2 = *(const f32x4*)(a2 + sc + 4);
        #pragma unroll
        for (int i = 0; i < 8; ++i) {
            float rv = (i < 4) ? u2[i] : v2[i - 4];
            xc[q][i] = bf2f((u16)hx[i]) + bf2f((u16)lx[i]) + rv;
            s += xc[q][i];
        }
    }
    s += __shfl_xor(s, 1); s += __shfl_xor(s, 2);
    float mu = s * (1.0f / 256.0f);
    float q2 = 0.f;
    #pragma unroll
    for (int q = 0; q < 8; ++q)
        #pragma unroll
        for (int i = 0; i < 8; ++i) { float e = xc[q][i] - mu; q2 += e * e; }
    q2 += __shfl_xor(q2, 1); q2 += __shfl_xor(q2, 2);
    float rs = rsqrtf(q2 * (1.0f / 256.0f) + 1e-5f);
    #pragma unroll
    for (int q = 0; q < 8; ++q) {
        int sc = q * 32 + kc;
        f32x4 g1 = *(const f32x4*)(l2g + sc);
        f32x4 g2v = *(const f32x4*)(l2g + sc + 4);
        f32x4 h1 = *(const f32x4*)(l2b + sc);
        f32x4 h2 = *(const f32x4*)(l2b + sc + 4);
        #pragma unroll
        for (int i = 0; i < 4; ++i) {
            xc[q][i]     = (xc[q][i]     - mu) * rs * g1[i]  + h1[i];
            xc[q][4 + i] = (xc[q][4 + i] - mu) * rs * g2v[i] + h2[i];
        }
    }

    f32x4 acc[4];
    #pragma unroll
    for (int i = 0; i < 4; ++i) acc[i] = (f32x4){0.f, 0.f, 0.f, 0.f};
    int lane = tid & 63, w = tid >> 6;
    int fr_ = lane & 15, kb0 = (lane >> 4) * 8;

    #pragma unroll        // xc must be statically indexed (no scratch)
    for (int kt = 0; kt < 16; ++kt) {
        int q = kt & 7, sc = q * 32 + kc;
        bool lo = kt >= 8;
        bf16x8 wv = *(const bf16x8*)(brow + sc);
        bf16x8 hv;
        #pragma unroll
        for (int i = 0; i < 8; ++i) {
            float v = xc[q][i];
            u16 hi = f2bf(v);
            hv[i] = (short)(lo ? f2bf(v - bf2f(hi)) : hi);
        }
        *(bf16x8*)&As[r][kc] = hv;
        *(bf16x8*)&Bs[r][kc] = wv;
        __syncthreads();
        bf16x8 bfrg = *(const bf16x8*)&Bs[w * 16 + fr_][kb0];
        #pragma unroll
        for (int mt = 0; mt < 4; ++mt) {
            bf16x8 afrg = *(const bf16x8*)&As[mt * 16 + fr_][kb0];
            acc[mt] = mfma16(afrg, bfrg, acc[mt]);
        }
        __syncthreads();
    }
    int col = n0 + w * 16 + fr_;
    float bvv = bias[col];
    int rq = (lane >> 4) * 4;
    #pragma unroll
    for (int mt = 0; mt < 4; ++mt)
        #pragma unroll
        for (int rr = 0; rr < 4; ++rr) {
            int mrow = m0 + mt * 16 + rq + rr;
            out[(size_t)mrow * 1024 + col] = acc[mt][rr] + bvv;
        }
}

// ---------------------------------------------------------------------------
// Stage-1 recurrence body (H=128). One barrier per step, C-domain gate
// fusion, hi/lo h in LDS dbuf, next-step xg prefetch.
// ---------------------------------------------------------------------------
DEV void recur1_body(SMemU* smu, int bid,
    const float* __restrict__ xgf, const float* __restrict__ xgr,
    const float* __restrict__ whhf, const float* __restrict__ whhr,
    float* __restrict__ cbf, float* __restrict__ cbr,
    float* __restrict__ hpf, float* __restrict__ hpr,
    float* __restrict__ xout, int s0, int s1)
{
    __builtin_amdgcn_s_setprio(1);
    constexpr int K = 128, N4 = 512;
    auto& Al = smu->r1.Al;

    int tid = threadIdx.x, lane = tid & 63, w = tid >> 6;
    int fr_ = lane & 15, quad = lane >> 4, kb0 = quad * 8;
    int dir = bid >> 5, gidx = bid & 31;
    const float* xg  = dir ? xgr  : xgf;
    const float* whh = dir ? whhr : whhf;
    float* cb = dir ? cbr : cbf;
    float* hp = dir ? hpr : hpf;
    int coloff = dir ? 128 : 0;

    bf16x8 bf[4][2][4];
    #pragma unroll
    for (int g = 0; g < 4; ++g)
        #pragma unroll
        for (int u = 0; u < 2; ++u) {
            const float* src = whh + (size_t)(g * K + w * 32 + u * 16 + fr_) * K;
            #pragma unroll
            for (int kt = 0; kt < 4; ++kt) {
                f32x4 a = *(const f32x4*)(src + kt * 32 + kb0);
                f32x4 b = *(const f32x4*)(src + kt * 32 + kb0 + 4);
                bf16x8 wv;
                #pragma unroll
                for (int i = 0; i < 8; ++i) wv[i] = (short)f2bf((i < 4) ? a[i] : b[i - 4]);
                bf[g][u][kt] = wv;
            }
        }

    int uq = quad >> 1, qrow = quad & 1;
    int colw = w * 32 + uq * 16 + fr_;        // 0..127
    int b0 = gidx * 8;
    float c[4];
    #pragma unroll
    for (int rr = 0; rr < 4; ++rr)
        c[rr] = (s0 > 0) ? cb[(size_t)(b0 + qrow * 4 + rr) * K + colw] : 0.f;

    if (s0 > 0) {   // preload h (fp32) into Al[s0&1] hi/lo
        for (int idx = tid; idx < 8 * K; idx += 256) {
            int sa = idx >> 7, k = idx & 127;
            float v = hp[(size_t)(b0 + sa) * K + k];
            u16 hh = f2bf(v);
            Al[s0 & 1][sa][k] = hh;
            Al[s0 & 1][8 + sa][k] = f2bf(v - bf2f(hh));
        }
    }
    __syncthreads();

    // prefetch xg for the first step
    float xv[4][4];
    {
        int xrow = dir ? (s1 - 1 - s0) : 0;
        #pragma unroll
        for (int rr = 0; rr < 4; ++rr) {
            const float* xp = xg + ((size_t)(xrow * 256 + b0 + qrow * 4 + rr)) * N4 + colw;
            #pragma unroll
            for (int g = 0; g < 4; ++g) xv[rr][g] = xp[g * K];
        }
    }

    for (int t = s0; t < s1; ++t) {
        float xn[4][4];
        {
            int tn = (t + 1 < s1) ? (t + 1) : t;
            int xrow = dir ? (s1 - 1 - tn) : (tn - s0);
            #pragma unroll
            for (int rr = 0; rr < 4; ++rr) {
                const float* xp = xg + ((size_t)(xrow * 256 + b0 + qrow * 4 + rr)) * N4 + colw;
                #pragma unroll
                for (int g = 0; g < 4; ++g) xn[rr][g] = xp[g * K];
            }
        }
        f32x4 acc[4][2];
        if (t > 0) {
            #pragma unroll
            for (int g = 0; g < 4; ++g)
                #pragma unroll
                for (int u = 0; u < 2; ++u) acc[g][u] = (f32x4){0.f, 0.f, 0.f, 0.f};
            #pragma unroll
            for (int kt = 0; kt < 4; ++kt) {
                bf16x8 a = *(const bf16x8*)&Al[t & 1][fr_][kt * 32 + kb0];
                #pragma unroll
                for (int g = 0; g < 4; ++g)
                    #pragma unroll
                    for (int u = 0; u < 2; ++u) acc[g][u] = mfma16(a, bf[g][u][kt], acc[g][u]);
            }
            // combine hi (quads 0,1) + lo (quads 2,3): UNIFORM indices only
            #pragma unroll
            for (int g = 0; g < 4; ++g)
                #pragma unroll
                for (int u = 0; u < 2; ++u)
                    #pragma unroll
                    for (int rr = 0; rr < 4; ++rr)
                        acc[g][u][rr] += __shfl_xor(acc[g][u][rr], 32);
        }
        int tt = dir ? (255 - t) : t;
        #pragma unroll
        for (int rr = 0; rr < 4; ++rr) {
            int s = qrow * 4 + rr;
            float gg[4];
            #pragma unroll
            for (int g = 0; g < 4; ++g) {
                float pv = (t > 0) ? (uq ? acc[g][1][rr] : acc[g][0][rr]) : 0.f;
                gg[g] = xv[rr][g] + pv;
            }
            c[rr] = fsig(gg[1]) * c[rr] + fsig(gg[0]) * ftanh(gg[2]);
            float h = fsig(gg[3]) * ftanh(c[rr]);
            u16 hh = f2bf(h);
            Al[(t + 1) & 1][s][colw] = hh;
            Al[(t + 1) & 1][8 + s][colw] = f2bf(h - bf2f(hh));
            xout[((size_t)tt * 256 + b0 + s) * 256 + coloff + colw] = h;
            if (t == s1 - 1) hp[(size_t)(b0 + s) * K + colw] = h;
        }
        __syncthreads();
        #pragma unroll
        for (int rr = 0; rr < 4; ++rr)
            #pragma unroll
            for (int g = 0; g < 4; ++g) xv[rr][g] = xn[rr][g];
    }
    #pragma unroll
    for (int rr = 0; rr < 4; ++rr)
        cb[(size_t)(b0 + qrow * 4 + rr) * K + colw] = c[rr];
}

// ---------------------------------------------------------------------------
// H2 recurrence body (K=256). 64-bit tagged agent-atomic h exchange, one
// barrier/step, next-step xg prefetch, s_sleep-throttled spin.
// OUTY 0: write h to chunk-local buffer. OUTY 1: write y at t==lastidx[b].
// ---------------------------------------------------------------------------
template<int OUTY>
DEV void recur2_body(SMemU* smu, int bid,
    const float* __restrict__ xg, const float* __restrict__ whh,
    float* __restrict__ cb, u64* hb,
    float* __restrict__ xoutc, float* __restrict__ yout,
    const int* __restrict__ lastidx,
    const float* __restrict__ bng, const float* __restrict__ bnb,
    int s0, int s1)
{
    __builtin_amdgcn_s_setprio(1);
    constexpr int K = 256, MB = 8, N4 = 1024;
    constexpr int CNT = MB * K / 256;   // 8 poll words per thread
    auto& Al = smu->r2.Al;

    int tid = threadIdx.x, lane = tid & 63, w = tid >> 6;
    int fr_ = lane & 15, quad = lane >> 4, kb0 = quad * 8;
    int group = bid >> 2, cw = bid & 3;
    u64* hbg = hb + (size_t)group * (2 * MB * K);
    int col = cw * 64 + w * 16 + fr_;         // 0..255

    bf16x8 bf[4][8];
    #pragma unroll
    for (int g = 0; g < 4; ++g) {
        const float* src = whh + (size_t)(g * 256 + col) * K;
        #pragma unroll
        for (int kt = 0; kt < 8; ++kt) {
            f32x4 a = *(const f32x4*)(src + kt * 32 + kb0);
            f32x4 b = *(const f32x4*)(src + kt * 32 + kb0 + 4);
            bf16x8 wv;
            #pragma unroll
            for (int i = 0; i < 8; ++i) wv[i] = (short)f2bf((i < 4) ? a[i] : b[i - 4]);
            bf[g][kt] = wv;
        }
    }

    int qrow = quad & 1, rhalf = quad >> 1;
    int sp[2], bs[2]; float c[2];
    #pragma unroll
    for (int j = 0; j < 2; ++j) {
        sp[j] = qrow * 4 + rhalf * 2 + j;     // sample-local 0..7
        bs[j] = group * 8 + sp[j];
        c[j] = (s0 > 0) ? cb[(size_t)bs[j] * K + col] : 0.f;
    }
    int lastb[2] = { -1, -1 };
    float bngv = 0.f, bnbv = 0.f;
    if (OUTY) {
        bool is64 = (lastidx[1] | lastidx[3] | lastidx[5] | lastidx[7] |
                     lastidx[9] | lastidx[11] | lastidx[13] | lastidx[15]) == 0;
        lastb[0] = is64 ? lastidx[2 * bs[0]] : lastidx[bs[0]];
        lastb[1] = is64 ? lastidx[2 * bs[1]] : lastidx[bs[1]];
        bngv = bng[col] * rsqrtf(1.0f + 1e-5f);
        bnbv = bnb[col];
    }

    // prefetch xg for the first step
    float xv[2][4];
    #pragma unroll
    for (int j = 0; j < 2; ++j) {
        const float* xp = xg + ((size_t)bs[j]) * N4 + col;
        #pragma unroll
        for (int g = 0; g < 4; ++g) xv[j][g] = xp[g * 256];
    }

    for (int t = s0; t < s1; ++t) {
        // issue next-step xg loads early
        float xn[2][4];
        {
            int tn = (t + 1 < s1) ? (t + 1) : t;
            int xr = tn - s0;
            #pragma unroll
            for (int j = 0; j < 2; ++j) {
                const float* xp = xg + ((size_t)(xr * 256 + bs[j])) * N4 + col;
                #pragma unroll
                for (int g = 0; g < 4; ++g) xn[j][g] = xp[g * 256];
            }
        }
        f32x4 acc[4];
        if (t > 0) {
            u64* hsrc = hbg + (size_t)(t & 1) * (MB * K);
            u64 v[CNT];
            #pragma unroll
            for (int i = 0; i < CNT; ++i)
                v[i] = __hip_atomic_load(hsrc + tid + i * 256,
                                         __ATOMIC_RELAXED, __HIP_MEMORY_SCOPE_AGENT);
            for (;;) {
                bool ok = true;
                #pragma unroll
                for (int i = 0; i < CNT; ++i)
                    if ((unsigned int)(v[i] >> 32) != (unsigned int)t) ok = false;
                if (ok) break;
                __builtin_amdgcn_s_sleep(1);   // throttle spin
                #pragma unroll
                for (int i = 0; i < CNT; ++i)
                    if ((unsigned int)(v[i] >> 32) != (unsigned int)t)
                        v[i] = __hip_atomic_load(hsrc + tid + i * 256,
                                                 __ATOMIC_RELAXED, __HIP_MEMORY_SCOPE_AGENT);
            }
            // stage: word idx = tid + i*256 -> sample i, col tid
            #pragma unroll
            for (int i = 0; i < CNT; ++i) {
                unsigned int d = (unsigned int)v[i];
                Al[i][tid]     = (u16)(d & 0xffffu);
                Al[8 + i][tid] = (u16)(d >> 16);
            }
            __syncthreads();
            #pragma unroll
            for (int g = 0; g < 4; ++g) acc[g] = (f32x4){0.f, 0.f, 0.f, 0.f};
            #pragma unroll
            for (int kt = 0; kt < 8; ++kt) {
                bf16x8 a = *(const bf16x8*)&Al[fr_][kt * 32 + kb0];
                #pragma unroll
                for (int g = 0; g < 4; ++g) acc[g] = mfma16(a, bf[g][kt], acc[g]);
            }
            // combine hi (quads 0,1) + lo (quads 2,3): UNIFORM indices only
            #pragma unroll
            for (int g = 0; g < 4; ++g)
                #pragma unroll
                for (int rr = 0; rr < 4; ++rr)
                    acc[g][rr] += __shfl_xor(acc[g][rr], 32);
        }
        #pragma unroll
        for (int j = 0; j < 2; ++j) {
            float gg[4];
            #pragma unroll
            for (int g = 0; g < 4; ++g) {
                float pv = (t > 0) ? (rhalf ? acc[g][2 + j] : acc[g][j]) : 0.f;
                gg[g] = xv[j][g] + pv;
            }
            c[j] = fsig(gg[1]) * c[j] + fsig(gg[0]) * ftanh(gg[2]);
            float h = fsig(gg[3]) * ftanh(c[j]);
            u16 hh = f2bf(h);
            u16 hl = f2bf(h - bf2f(hh));
            u64 word = (u64)((unsigned int)hh | ((unsigned int)hl << 16))
                     | ((u64)(unsigned int)(t + 1) << 32);
            __hip_atomic_store(hbg + (size_t)((t + 1) & 1) * (MB * K) + (size_t)sp[j] * K + col,
                               word, __ATOMIC_RELAXED, __HIP_MEMORY_SCOPE_AGENT);
            if (OUTY == 0) {
                xoutc[((size_t)(t - s0) * 256 + bs[j]) * 256 + col] = h;
            } else if (t == lastb[j]) {
                float y = h * bngv + bnbv;
                y = y > 0.f ? y : 0.f;
                yout[(size_t)bs[j] * 256 + col] = y;
            }
        }
        #pragma unroll
        for (int j = 0; j < 2; ++j)
            #pragma unroll
            for (int g = 0; g < 4; ++g) xv[j][g] = xn[j][g];
    }
    #pragma unroll
    for (int j = 0; j < 2; ++j) cb[(size_t)bs[j] * K + col] = c[j];
}

// ---------------------------------------------------------------------------
// Fused stage-1 launch (r1 layout): blocks [0,64) recur1(chunk i-1),
// [64,2112) xg_fr(chunk i).
// ---------------------------------------------------------------------------
__global__ __launch_bounds__(256) void fused1_kernel(
    const float* __restrict__ embed,
    const u16* __restrict__ Wf16, const float* __restrict__ bfb,
    const u16* __restrict__ Wr16, const float* __restrict__ brb,
    float* __restrict__ xgfw, float* __restrict__ xgrw, int t0f, int t0r, int gon,
    const float* __restrict__ xgfr, const float* __restrict__ xgrr,
    const float* __restrict__ whhf, const float* __restrict__ whhr,
    float* __restrict__ cbf, float* __restrict__ cbr,
    float* __restrict__ hpf, float* __restrict__ hpr,
    float* __restrict__ X1, int s0, int s1, int ron)
{
    __shared__ SMemU sm;
    int b = blockIdx.x;
    if (b < 64) {
        if (ron)
            recur1_body(&sm, b, xgfr, xgrr, whhf, whhr, cbf, cbr, hpf, hpr, X1, s0, s1);
    } else {
        if (gon) {
            int idx = b - 64;
            xg_fr_body(&sm, idx & 7, idx >> 3, 256, embed, Wf16, bfb, Wr16, brb,
                       xgfw, xgrw, t0f, t0r);
        }
    }
}

// ---------------------------------------------------------------------------
// Fused stage-2/3 slot launch (r1 layout):
//  [0,128)        recur2 layer-1 (OUTY=0) chunk i     -> R[i&1]
//  [128,256)      recur2 layer-2 (OUTY=1) chunk i-2   -> y
//  [256,1280)     lean xg layer-1 chunk i+1           -> G2[(i+1)&1]
//  [1280,2304)    xg layer-2 (+res+ln2) chunk i-1     -> G3[(i-1)&1]
// ---------------------------------------------------------------------------
__global__ __launch_bounds__(256) void fused2_kernel(
    const float* __restrict__ xg2, const float* __restrict__ w1hh,
    float* __restrict__ cb1, u64* hb1, float* __restrict__ Rw,
    int s2a, int s2b, int s2on,
    const float* __restrict__ xg3, const float* __restrict__ w2hh,
    float* __restrict__ cb2, u64* hb2, float* __restrict__ yout,
    const int* __restrict__ lastidx, const float* __restrict__ bng,
    const float* __restrict__ bnb, int s3a, int s3b, int s3on,
    const u16* __restrict__ X1p, const u16* __restrict__ w1p,
    const float* __restrict__ b1, float* __restrict__ G2w, int g2t0, int g2on,
    const float* __restrict__ Rr, const float* __restrict__ ln2g,
    const float* __restrict__ ln2b, const u16* __restrict__ w2p,
    const float* __restrict__ b2v, float* __restrict__ G3w, int g3t0, int g3on)
{
    __shared__ SMemU sm;
    int b = blockIdx.x;
    if (b < 128) {
        if (s2on)
            recur2_body<0>(&sm, b, xg2, w1hh, cb1, hb1, Rw,
                           nullptr, nullptr, nullptr, nullptr, s2a, s2b);
    } else if (b < 256) {
        if (s3on)
            recur2_body<1>(&sm, b - 128, xg3, w2hh, cb2, hb2,
                           nullptr, yout, lastidx, bng, bnb, s3a, s3b);
    } else if (b < 1280) {
        if (g2on) {
            int i = b - 256;
            xg_l16_body(&sm, i & 15, i >> 4, X1p, w1p, b1, G2w, g2t0);
        }
    } else {
        if (g3on) {
            int i = b - 1280;
            xg_ln3_body(&sm, i & 15, i >> 4, X1p, Rr, ln2g, ln2b, w2p, b2v, G3w, g3t0);
        }
    }
}

// standalone lean layer-2 xg GEMM for chunk 0 (after prep_x1)
__global__ __launch_bounds__(256) void xg2_kernel(
    const u16* __restrict__ X1p, const u16* __restrict__ Wp,
    const float* __restrict__ bias, float* __restrict__ out, int t0)
{
    __shared__ SMemU sm;
    xg_l16_body(&sm, blockIdx.x, blockIdx.y, X1p, Wp, bias, out, t0);
}

// ---------------------------------------------------------------------------
// Launch
// ---------------------------------------------------------------------------
extern "C" void kernel_launch(void* const* d_in, const int* in_sizes, int n_in,
                              void* d_out, int out_size, void* d_ws, size_t ws_size,
                              hipStream_t stream)
{
    (void)in_sizes; (void)n_in; (void)out_size; (void)ws_size;
    const float* embed = (const float*)d_in[0];
    const int* lastidx = (const int*)d_in[1];
    const float* Wih_f = (const float*)d_in[2];
    const float* Whh_f = (const float*)d_in[3];
    const float* b_f   = (const float*)d_in[4];
    const float* Wih_r = (const float*)d_in[5];
    const float* Whh_r = (const float*)d_in[6];
    const float* b_r   = (const float*)d_in[7];
    const float* ln1g  = (const float*)d_in[8];
    const float* ln1b  = (const float*)d_in[9];
    const float* W1ih  = (const float*)d_in[10];
    const float* W1hh  = (const float*)d_in[11];
    const float* b1    = (const float*)d_in[12];
    const float* ln2g  = (const float*)d_in[13];
    const float* ln2b  = (const float*)d_in[14];
    const float* W2ih  = (const float*)d_in[15];
    const float* W2hh  = (const float*)d_in[16];
    const float* b2    = (const float*)d_in[17];
    const float* bng   = (const float*)d_in[18];
    const float* bnb   = (const float*)d_in[19];

    const size_t MiB = 1024 * 1024;
    char* ws = (char*)d_ws;
    float* G2[2] = { (float*)ws,               (float*)(ws + 16 * MiB) };
    float* G3[2] = { (float*)(ws + 32 * MiB),  (float*)(ws + 48 * MiB) };
    float* X1    =   (float*)(ws + 64 * MiB);   // 64 MiB; ln1 bf16 planes in place after prep
    float* R[2]  = { (float*)(ws + 128 * MiB), (float*)(ws + 132 * MiB) };  // 4 MiB each
    char* p = ws + 136 * MiB;
    u64* hb1 = (u64*)p;                         p += 1024 * 1024;
    u64* hb2 = (u64*)p;                         p += 1024 * 1024;
    float* cbf = (float*)p;                     p += 128 * 1024;
    float* cbr = (float*)p;                     p += 128 * 1024;
    float* cb1 = (float*)p;                     p += 256 * 1024;
    float* cb2 = (float*)p;                     p += 256 * 1024;
    float* hpf = (float*)p;                     p += 128 * 1024;
    float* hpr = (float*)p;                     p += 128 * 1024;
    u16* w1p   = (u16*)p;                       p += 512 * 1024;   // W1ih bf16 [1024][256]
    u16* w2p   = (u16*)p;                       p += 512 * 1024;   // W2ih bf16
    u16* wfp   = (u16*)p;                       p += 128 * 1024;   // Wih_f bf16 [512][128]
    u16* wrp   = (u16*)p;                       // Wih_r bf16

    const int CH1 = 32, n1 = 8;    // stage-1 chunking
    const int CH  = 16, n2 = 16;   // stage-2/3 chunking

    // one-time weight conversions
    prep_w_kernel<<<1024, 256, 0, stream>>>(W1ih, w1p, 262144);
    prep_w_kernel<<<1024, 256, 0, stream>>>(W2ih, w2p, 262144);
    prep_w_kernel<<<256, 256, 0, stream>>>(Wih_f, wfp, 65536);
    prep_w_kernel<<<256, 256, 0, stream>>>(Wih_r, wrp, 65536);

    // stage 1: bidirectional H=128 LSTM -> X1 (raw concat)
    for (int i = 0; i <= n1; ++i) {
        int gon = (i < n1), ron = (i >= 1);
        float* wf = (i & 1) ? G3[0] : G2[0];
        float* wr = (i & 1) ? G3[1] : G2[1];
        const float* rf = ((i - 1) & 1) ? G3[0] : G2[0];
        const float* rr_ = ((i - 1) & 1) ? G3[1] : G2[1];
        fused1_kernel<<<2112, 256, 0, stream>>>(
            embed, wfp, b_f, wrp, b_r, wf, wr, CH1 * i, 256 - CH1 * (i + 1), gon,
            rf, rr_, Whh_f, Whh_r, cbf, cbr, hpf, hpr, X1, CH1 * (i - 1), CH1 * i, ron);
    }

    // ln1 + bf16 hi/lo split, in place over X1
    prep_x1_kernel<<<16384, 256, 0, stream>>>(X1, ln1g, ln1b);
    const u16* X1p = (const u16*)X1;

    // stages 2+3, deep pipeline
    xg2_kernel<<<dim3(16, CH * 4), 256, 0, stream>>>(X1p, w1p, b1, G2[0], 0);
    for (int i = 0; i <= n2 + 1; ++i) {
        int s2on = (i < n2), s3on = (i >= 2);
        int g2on = (i + 1 < n2), g3on = (i >= 1 && i <= n2);
        fused2_kernel<<<2304, 256, 0, stream>>>(
            G2[i & 1], W1hh, cb1, hb1, R[i & 1], CH * i, CH * (i + 1), s2on,
            G3[(i - 2) & 1], W2hh, cb2, hb2, (float*)d_out, lastidx, bng, bnb,
            CH * (i - 2), CH * (i - 1), s3on,
            X1p, w1p, b1, G2[(i + 1) & 1], CH * (i + 1), g2on,
            R[(i - 1) & 1], ln2g, ln2b, w2p, b2, G3[(i - 1) & 1], CH * (i - 1), g3on);
    }
}

// Round 5
// 1996.924 us; speedup vs baseline: 1.8596x; 1.2033x over previous
//
#include <hip/hip_runtime.h>
#include <cstdint>
#include <cstddef>

typedef unsigned short u16;
typedef unsigned long long u64;
typedef __attribute__((ext_vector_type(8))) short bf16x8;  // 8 x bf16 (4 VGPRs)
typedef __attribute__((ext_vector_type(4))) float f32x4;
typedef __attribute__((ext_vector_type(4))) unsigned short u16x4;

#define DEV __device__ __forceinline__

DEV float bf2f(u16 h) { union { unsigned int u; float f; } x; x.u = ((unsigned int)h) << 16; return x.f; }
DEV u16 f2bf(float f) {
    union { float f; unsigned int u; } x; x.f = f;
    unsigned int u = x.u;
    return (u16)((u + 0x7fffu + ((u >> 16) & 1u)) >> 16);   // RNE
}
// fast gate math: __expf + v_rcp_f32; rel err ~1e-6 << bf16 weight rounding
DEV float fsig(float x)  { float e = __expf(-x);      return __builtin_amdgcn_rcpf(1.0f + e); }
DEV float ftanh(float x) { float e = __expf(2.0f * x); return 1.0f - 2.0f * __builtin_amdgcn_rcpf(e + 1.0f); }
DEV f32x4 mfma16(bf16x8 a, bf16x8 b, f32x4 c) {
    return __builtin_amdgcn_mfma_f32_16x16x32_bf16(a, b, c, 0, 0, 0);
}

// B=256, T=256, E=128, H=128 (per direction), H2=256. ALL tensors fp32.
//
// r13 (round 5): r4 post-mortem — chain CUs host NO GEMM blocks (2/CU x 2304
// blocks => chain owns CUs 0-127), so residual chain inflation is MEMORY-
// SYSTEM contention; FETCH arithmetic says the h-exchange (each group's 16KB
// tile re-fetched by 4 blocks on 4 DIFFERENT XCDs through the MALL) is the
// largest L2-fill stream, and the 2048-small-block GEMM wall co-binds.
// Changes: (1) same-XCD group mapping for recur2 blocks (b = x+8k relabel;
// pure permutation); (2) 64x128 double-wide GEMM tiles (one A-stage, two
// B-subtiles, 8 MFMA/barrier-pair, 1024 blocks); (3) all Whh pre-converted
// to bf16 (kills per-launch fp32 load + f2bf storm in every recurrence).

union __align__(16) SMemU {
    struct { u16 As[64][40]; u16 Bs[128][40]; } g;  // GEMM staging (15360 B)
    struct { u16 Al[2][16][136]; } r1;              // recur1 h dbuf (8704 B)
    struct { u16 Al[16][264]; } r2;                 // recur2 h stage (8448 B)
};

// ---------------------------------------------------------------------------
// prep: fp32 -> bf16 conversion for 4 arrays in one launch (counts in
// 256-element blocks; all sizes here are multiples of 256)
// ---------------------------------------------------------------------------
__global__ __launch_bounds__(256) void prep_w4_kernel(
    const float* __restrict__ a0, u16* __restrict__ o0, int c0,
    const float* __restrict__ a1, u16* __restrict__ o1, int c1,
    const float* __restrict__ a2, u16* __restrict__ o2, int c2,
    const float* __restrict__ a3, u16* __restrict__ o3)
{
    int blk = blockIdx.x;
    const float* a; u16* o; int off;
    if (blk < c0)                { a = a0; o = o0; off = blk; }
    else if (blk < c0 + c1)      { a = a1; o = o1; off = blk - c0; }
    else if (blk < c0 + c1 + c2) { a = a2; o = o2; off = blk - c0 - c1; }
    else                         { a = a3; o = o3; off = blk - c0 - c1 - c2; }
    int i = off * 256 + threadIdx.x;
    o[i] = f2bf(a[i]);
}

// ---------------------------------------------------------------------------
// prep: ln1 over X1 rows, store bf16 hi/lo planes IN PLACE over the row.
// Row r (1KB): bytes [0,512) = H plane u16[256], [512,1024) = L plane.
// One wave per row: loads complete (waitcnt) before any store issues.
// ---------------------------------------------------------------------------
__global__ __launch_bounds__(256) void prep_x1_kernel(
    float* __restrict__ X, const float* __restrict__ gw, const float* __restrict__ bw)
{
    int row  = blockIdx.x * 4 + (threadIdx.x >> 6);
    int lane = threadIdx.x & 63;
    float* xr = X + (size_t)row * 256;
    f32x4 v = *(const f32x4*)(xr + lane * 4);
    float s = v[0] + v[1] + v[2] + v[3];
    #pragma unroll
    for (int mm = 1; mm < 64; mm <<= 1) s += __shfl_xor(s, mm, 64);
    float mu = s * (1.0f / 256.0f);
    f32x4 e = v - mu;
    float q = e[0]*e[0] + e[1]*e[1] + e[2]*e[2] + e[3]*e[3];
    #pragma unroll
    for (int mm = 1; mm < 64; mm <<= 1) q += __shfl_xor(q, mm, 64);
    float rs = rsqrtf(q * (1.0f / 256.0f) + 1e-5f);
    int c0 = lane * 4;
    u16x4 hv, lv;
    #pragma unroll
    for (int i = 0; i < 4; ++i) {
        float o = e[i] * rs * gw[c0 + i] + bw[c0 + i];
        u16 hh = f2bf(o);
        hv[i] = hh;
        lv[i] = f2bf(o - bf2f(hh));
    }
    u16* H = (u16*)xr;
    *(u16x4*)(H + lane * 4)       = hv;
    *(u16x4*)(H + 256 + lane * 4) = lv;
}

// ---------------------------------------------------------------------------
// xg GEMM body, first (bi) layer. A = embed fp32 (split on the fly),
// W = pre-converted bf16. 64x64 tile (K=128 layer, cheap already).
// ---------------------------------------------------------------------------
DEV void xg_fr_body(SMemU* smu, int bx, int by, int nby,
    const float* __restrict__ embed,
    const u16* __restrict__ Wf16, const float* __restrict__ bf_,
    const u16* __restrict__ Wr16, const float* __restrict__ br_,
    float* __restrict__ xgf, float* __restrict__ xgr, int t0f, int t0r)
{
    auto& As = smu->g.As;
    auto& Bs = smu->g.Bs;
    int tid = threadIdx.x;
    int half = nby >> 1;
    bool isR = by >= half;
    int m0 = (by - (isR ? half : 0)) * 64;
    const u16* W      = isR ? Wr16 : Wf16;
    const float* bias = isR ? br_ : bf_;
    float* out        = isR ? xgr : xgf;
    int tbase         = isR ? t0r : t0f;
    int n0 = bx * 64;

    int r  = tid >> 2;
    int kc = (tid & 3) * 8;
    int m  = m0 + r;
    int tl = m >> 8, bb = m & 255;
    const float* arow = embed + ((size_t)(bb * 256 + (tbase + tl)) * 128);
    const u16* brow = W + ((size_t)(n0 + r) * 128);

    f32x4 acc[4];
    #pragma unroll
    for (int i = 0; i < 4; ++i) acc[i] = (f32x4){0.f, 0.f, 0.f, 0.f};
    int lane = tid & 63, w = tid >> 6;
    int fr_ = lane & 15, kb0 = (lane >> 4) * 8;

    for (int kt = 0; kt < 8; ++kt) {
        int sc = (kt & 3) * 32 + kc;
        bool lo = kt >= 4;
        f32x4 va = *(const f32x4*)(arow + sc);
        f32x4 vb = *(const f32x4*)(arow + sc + 4);
        bf16x8 wv = *(const bf16x8*)(brow + sc);
        bf16x8 hv;
        #pragma unroll
        for (int i = 0; i < 8; ++i) {
            float v = (i < 4) ? va[i] : vb[i - 4];
            u16 hi = f2bf(v);
            hv[i] = (short)(lo ? f2bf(v - bf2f(hi)) : hi);
        }
        *(bf16x8*)&As[r][kc] = hv;
        *(bf16x8*)&Bs[r][kc] = wv;
        __syncthreads();
        bf16x8 bfrg = *(const bf16x8*)&Bs[w * 16 + fr_][kb0];
        #pragma unroll
        for (int mt = 0; mt < 4; ++mt) {
            bf16x8 afrg = *(const bf16x8*)&As[mt * 16 + fr_][kb0];
            acc[mt] = mfma16(afrg, bfrg, acc[mt]);
        }
        __syncthreads();
    }
    int col = n0 + w * 16 + fr_;
    float bvv = bias[col];
    int rq = (lane >> 4) * 4;
    #pragma unroll
    for (int mt = 0; mt < 4; ++mt)
        #pragma unroll
        for (int rr = 0; rr < 4; ++rr) {
            int mrow = m0 + mt * 16 + rq + rr;
            out[(size_t)mrow * 512 + col] = acc[mt][rr] + bvv;
        }
}

// ---------------------------------------------------------------------------
// LEAN layer-2 xg GEMM, 64x128 tile: one A-stage feeds TWO 64-col B-subtiles
// (8 MFMA per barrier pair). A = bf16 hi/lo planes of ln1(X1); W = bf16.
// ---------------------------------------------------------------------------
DEV void xg_l16_body(SMemU* smu, int bx, int by,
    const u16* __restrict__ X1p, const u16* __restrict__ Wp,
    const float* __restrict__ bias, float* __restrict__ out, int t0)
{
    auto& As = smu->g.As;
    auto& Bs = smu->g.Bs;     // [128][40]
    int tid = threadIdx.x;
    int m0 = by * 64, n0 = bx * 128;
    int rA = tid >> 2, kcA = (tid & 3) * 8;
    int rB = tid >> 1, kcB = (tid & 1) * 16;
    int m  = m0 + rA;
    int tl = m >> 8, bb = m & 255;
    const u16* arow = X1p + ((size_t)((t0 + tl) * 256 + bb)) * 512;  // H[256] then L[256]
    const u16* brow = Wp + ((size_t)(n0 + rB)) * 256;

    f32x4 acc[2][4];
    #pragma unroll
    for (int cs = 0; cs < 2; ++cs)
        #pragma unroll
        for (int i = 0; i < 4; ++i) acc[cs][i] = (f32x4){0.f, 0.f, 0.f, 0.f};
    int lane = tid & 63, w = tid >> 6;
    int fr_ = lane & 15, kb0 = (lane >> 4) * 8;

    for (int kt = 0; kt < 16; ++kt) {
        int sc = (kt & 7) * 32;
        bf16x8 hv  = *(const bf16x8*)(arow + ((kt >= 8) ? 256 : 0) + sc + kcA);
        bf16x8 wv0 = *(const bf16x8*)(brow + sc + kcB);
        bf16x8 wv1 = *(const bf16x8*)(brow + sc + kcB + 8);
        *(bf16x8*)&As[rA][kcA] = hv;
        *(bf16x8*)&Bs[rB][kcB] = wv0;
        *(bf16x8*)&Bs[rB][kcB + 8] = wv1;
        __syncthreads();
        bf16x8 b0 = *(const bf16x8*)&Bs[w * 16 + fr_][kb0];
        bf16x8 b1 = *(const bf16x8*)&Bs[64 + w * 16 + fr_][kb0];
        #pragma unroll
        for (int mt = 0; mt < 4; ++mt) {
            bf16x8 afrg = *(const bf16x8*)&As[mt * 16 + fr_][kb0];
            acc[0][mt] = mfma16(afrg, b0, acc[0][mt]);
            acc[1][mt] = mfma16(afrg, b1, acc[1][mt]);
        }
        __syncthreads();
    }
    int rq = (lane >> 4) * 4;
    #pragma unroll
    for (int cs = 0; cs < 2; ++cs) {
        int col = n0 + cs * 64 + w * 16 + fr_;
        float bvv = bias[col];
        #pragma unroll
        for (int mt = 0; mt < 4; ++mt)
            #pragma unroll
            for (int rr = 0; rr < 4; ++rr) {
                int mrow = m0 + mt * 16 + rq + rr;
                out[(size_t)mrow * 1024 + col] = acc[cs][mt][rr] + bvv;
            }
    }
}

// ---------------------------------------------------------------------------
// layer-3 xg GEMM, 64x128 tile: A = ln2( R + (H+L planes of ln1X1) ), W bf16.
// ---------------------------------------------------------------------------
DEV void xg_ln3_body(SMemU* smu, int bx, int by,
    const u16* __restrict__ X1p, const float* __restrict__ Rc,
    const float* __restrict__ l2g, const float* __restrict__ l2b,
    const u16* __restrict__ Wp, const float* __restrict__ bias,
    float* __restrict__ out, int t0)
{
    auto& As = smu->g.As;
    auto& Bs = smu->g.Bs;
    int tid = threadIdx.x;
    int m0 = by * 64, n0 = bx * 128;
    int rA = tid >> 2, kcA = (tid & 3) * 8;
    int rB = tid >> 1, kcB = (tid & 1) * 16;
    int m  = m0 + rA;
    int tl = m >> 8, bb = m & 255;
    const u16* a1 = X1p + ((size_t)((t0 + tl) * 256 + bb)) * 512;
    const float* a2 = Rc + ((size_t)(tl * 256 + bb)) * 256;
    const u16* brow = Wp + ((size_t)(n0 + rB)) * 256;

    float xc[8][8];
    float s = 0.f;
    #pragma unroll
    for (int q = 0; q < 8; ++q) {
        int sc = q * 32 + kcA;
        bf16x8 hx = *(const bf16x8*)(a1 + sc);
        bf16x8 lx = *(const bf16x8*)(a1 + 256 + sc);
        f32x4 u2 = *(const f32x4*)(a2 + sc);
        f32x4 v2 = *(const f32x4*)(a2 + sc + 4);
        #pragma unroll
        for (int i = 0; i < 8; ++i) {
            float rv = (i < 4) ? u2[i] : v2[i - 4];
            xc[q][i] = bf2f((u16)hx[i]) + bf2f((u16)lx[i]) + rv;
            s += xc[q][i];
        }
    }
    s += __shfl_xor(s, 1); s += __shfl_xor(s, 2);
    float mu = s * (1.0f / 256.0f);
    float q2 = 0.f;
    #pragma unroll
    for (int q = 0; q < 8; ++q)
        #pragma unroll
        for (int i = 0; i < 8; ++i) { float e = xc[q][i] - mu; q2 += e * e; }
    q2 += __shfl_xor(q2, 1); q2 += __shfl_xor(q2, 2);
    float rs = rsqrtf(q2 * (1.0f / 256.0f) + 1e-5f);
    #pragma unroll
    for (int q = 0; q < 8; ++q) {
        int sc = q * 32 + kcA;
        f32x4 g1 = *(const f32x4*)(l2g + sc);
        f32x4 g2v = *(const f32x4*)(l2g + sc + 4);
        f32x4 h1 = *(const f32x4*)(l2b + sc);
        f32x4 h2 = *(const f32x4*)(l2b + sc + 4);
        #pragma unroll
        for (int i = 0; i < 4; ++i) {
            xc[q][i]     = (xc[q][i]     - mu) * rs * g1[i]  + h1[i];
            xc[q][4 + i] = (xc[q][4 + i] - mu) * rs * g2v[i] + h2[i];
        }
    }

    f32x4 acc[2][4];
    #pragma unroll
    for (int cs = 0; cs < 2; ++cs)
        #pragma unroll
        for (int i = 0; i < 4; ++i) acc[cs][i] = (f32x4){0.f, 0.f, 0.f, 0.f};
    int lane = tid & 63, w = tid >> 6;
    int fr_ = lane & 15, kb0 = (lane >> 4) * 8;

    #pragma unroll        // xc must be statically indexed (no scratch)
    for (int kt = 0; kt < 16; ++kt) {
        int q = kt & 7, sc = q * 32;
        bool lo = kt >= 8;
        bf16x8 wv0 = *(const bf16x8*)(brow + sc + kcB);
        bf16x8 wv1 = *(const bf16x8*)(brow + sc + kcB + 8);
        bf16x8 hv;
        #pragma unroll
        for (int i = 0; i < 8; ++i) {
            float v = xc[q][i];
            u16 hi = f2bf(v);
            hv[i] = (short)(lo ? f2bf(v - bf2f(hi)) : hi);
        }
        *(bf16x8*)&As[rA][kcA] = hv;
        *(bf16x8*)&Bs[rB][kcB] = wv0;
        *(bf16x8*)&Bs[rB][kcB + 8] = wv1;
        __syncthreads();
        bf16x8 b0 = *(const bf16x8*)&Bs[w * 16 + fr_][kb0];
        bf16x8 b1 = *(const bf16x8*)&Bs[64 + w * 16 + fr_][kb0];
        #pragma unroll
        for (int mt = 0; mt < 4; ++mt) {
            bf16x8 afrg = *(const bf16x8*)&As[mt * 16 + fr_][kb0];
            acc[0][mt] = mfma16(afrg, b0, acc[0][mt]);
            acc[1][mt] = mfma16(afrg, b1, acc[1][mt]);
        }
        __syncthreads();
    }
    int rq = (lane >> 4) * 4;
    #pragma unroll
    for (int cs = 0; cs < 2; ++cs) {
        int col = n0 + cs * 64 + w * 16 + fr_;
        float bvv = bias[col];
        #pragma unroll
        for (int mt = 0; mt < 4; ++mt)
            #pragma unroll
            for (int rr = 0; rr < 4; ++rr) {
                int mrow = m0 + mt * 16 + rq + rr;
                out[(size_t)mrow * 1024 + col] = acc[cs][mt][rr] + bvv;
            }
    }
}

// ---------------------------------------------------------------------------
// Stage-1 recurrence body (H=128). One barrier per step, C-domain gate
// fusion, hi/lo h in LDS dbuf, next-step xg prefetch. Whh pre-converted bf16.
// ---------------------------------------------------------------------------
DEV void recur1_body(SMemU* smu, int bid,
    const float* __restrict__ xgf, const float* __restrict__ xgr,
    const u16* __restrict__ whf16, const u16* __restrict__ whr16,
    float* __restrict__ cbf, float* __restrict__ cbr,
    float* __restrict__ hpf, float* __restrict__ hpr,
    float* __restrict__ xout, int s0, int s1)
{
    __builtin_amdgcn_s_setprio(1);
    constexpr int K = 128, N4 = 512;
    auto& Al = smu->r1.Al;

    int tid = threadIdx.x, lane = tid & 63, w = tid >> 6;
    int fr_ = lane & 15, quad = lane >> 4, kb0 = quad * 8;
    int dir = bid >> 5, gidx = bid & 31;
    const float* xg  = dir ? xgr  : xgf;
    const u16* whh16 = dir ? whr16 : whf16;
    float* cb = dir ? cbr : cbf;
    float* hp = dir ? hpr : hpf;
    int coloff = dir ? 128 : 0;

    bf16x8 bf[4][2][4];
    #pragma unroll
    for (int g = 0; g < 4; ++g)
        #pragma unroll
        for (int u = 0; u < 2; ++u) {
            const u16* src = whh16 + (size_t)(g * K + w * 32 + u * 16 + fr_) * K;
            #pragma unroll
            for (int kt = 0; kt < 4; ++kt)
                bf[g][u][kt] = *(const bf16x8*)(src + kt * 32 + kb0);
        }

    int uq = quad >> 1, qrow = quad & 1;
    int colw = w * 32 + uq * 16 + fr_;        // 0..127
    int b0 = gidx * 8;
    float c[4];
    #pragma unroll
    for (int rr = 0; rr < 4; ++rr)
        c[rr] = (s0 > 0) ? cb[(size_t)(b0 + qrow * 4 + rr) * K + colw] : 0.f;

    if (s0 > 0) {   // preload h (fp32) into Al[s0&1] hi/lo
        for (int idx = tid; idx < 8 * K; idx += 256) {
            int sa = idx >> 7, k = idx & 127;
            float v = hp[(size_t)(b0 + sa) * K + k];
            u16 hh = f2bf(v);
            Al[s0 & 1][sa][k] = hh;
            Al[s0 & 1][8 + sa][k] = f2bf(v - bf2f(hh));
        }
    }
    __syncthreads();

    // prefetch xg for the first step
    float xv[4][4];
    {
        int xrow = dir ? (s1 - 1 - s0) : 0;
        #pragma unroll
        for (int rr = 0; rr < 4; ++rr) {
            const float* xp = xg + ((size_t)(xrow * 256 + b0 + qrow * 4 + rr)) * N4 + colw;
            #pragma unroll
            for (int g = 0; g < 4; ++g) xv[rr][g] = xp[g * K];
        }
    }

    for (int t = s0; t < s1; ++t) {
        float xn[4][4];
        {
            int tn = (t + 1 < s1) ? (t + 1) : t;
            int xrow = dir ? (s1 - 1 - tn) : (tn - s0);
            #pragma unroll
            for (int rr = 0; rr < 4; ++rr) {
                const float* xp = xg + ((size_t)(xrow * 256 + b0 + qrow * 4 + rr)) * N4 + colw;
                #pragma unroll
                for (int g = 0; g < 4; ++g) xn[rr][g] = xp[g * K];
            }
        }
        f32x4 acc[4][2];
        if (t > 0) {
            #pragma unroll
            for (int g = 0; g < 4; ++g)
                #pragma unroll
                for (int u = 0; u < 2; ++u) acc[g][u] = (f32x4){0.f, 0.f, 0.f, 0.f};
            #pragma unroll
            for (int kt = 0; kt < 4; ++kt) {
                bf16x8 a = *(const bf16x8*)&Al[t & 1][fr_][kt * 32 + kb0];
                #pragma unroll
                for (int g = 0; g < 4; ++g)
                    #pragma unroll
                    for (int u = 0; u < 2; ++u) acc[g][u] = mfma16(a, bf[g][u][kt], acc[g][u]);
            }
            // combine hi (quads 0,1) + lo (quads 2,3): UNIFORM indices only
            #pragma unroll
            for (int g = 0; g < 4; ++g)
                #pragma unroll
                for (int u = 0; u < 2; ++u)
                    #pragma unroll
                    for (int rr = 0; rr < 4; ++rr)
                        acc[g][u][rr] += __shfl_xor(acc[g][u][rr], 32);
        }
        int tt = dir ? (255 - t) : t;
        #pragma unroll
        for (int rr = 0; rr < 4; ++rr) {
            int s = qrow * 4 + rr;
            float gg[4];
            #pragma unroll
            for (int g = 0; g < 4; ++g) {
                float pv = (t > 0) ? (uq ? acc[g][1][rr] : acc[g][0][rr]) : 0.f;
                gg[g] = xv[rr][g] + pv;
            }
            c[rr] = fsig(gg[1]) * c[rr] + fsig(gg[0]) * ftanh(gg[2]);
            float h = fsig(gg[3]) * ftanh(c[rr]);
            u16 hh = f2bf(h);
            Al[(t + 1) & 1][s][colw] = hh;
            Al[(t + 1) & 1][8 + s][colw] = f2bf(h - bf2f(hh));
            xout[((size_t)tt * 256 + b0 + s) * 256 + coloff + colw] = h;
            if (t == s1 - 1) hp[(size_t)(b0 + s) * K + colw] = h;
        }
        __syncthreads();
        #pragma unroll
        for (int rr = 0; rr < 4; ++rr)
            #pragma unroll
            for (int g = 0; g < 4; ++g) xv[rr][g] = xn[rr][g];
    }
    #pragma unroll
    for (int rr = 0; rr < 4; ++rr)
        cb[(size_t)(b0 + qrow * 4 + rr) * K + colw] = c[rr];
}

// ---------------------------------------------------------------------------
// H2 recurrence body (K=256). 64-bit tagged agent-atomic h exchange, one
// barrier/step, next-step xg prefetch, s_sleep-throttled spin. Whh bf16.
// OUTY 0: write h to chunk-local buffer. OUTY 1: write y at t==lastidx[b].
// ---------------------------------------------------------------------------
template<int OUTY>
DEV void recur2_body(SMemU* smu, int bid,
    const float* __restrict__ xg, const u16* __restrict__ whh16,
    float* __restrict__ cb, u64* hb,
    float* __restrict__ xoutc, float* __restrict__ yout,
    const int* __restrict__ lastidx,
    const float* __restrict__ bng, const float* __restrict__ bnb,
    int s0, int s1)
{
    __builtin_amdgcn_s_setprio(1);
    constexpr int K = 256, MB = 8, N4 = 1024;
    constexpr int CNT = MB * K / 256;   // 8 poll words per thread
    auto& Al = smu->r2.Al;

    int tid = threadIdx.x, lane = tid & 63, w = tid >> 6;
    int fr_ = lane & 15, quad = lane >> 4, kb0 = quad * 8;
    int group = bid >> 2, cw = bid & 3;
    u64* hbg = hb + (size_t)group * (2 * MB * K);
    int col = cw * 64 + w * 16 + fr_;         // 0..255

    bf16x8 bf[4][8];
    #pragma unroll
    for (int g = 0; g < 4; ++g) {
        const u16* src = whh16 + (size_t)(g * 256 + col) * K;
        #pragma unroll
        for (int kt = 0; kt < 8; ++kt)
            bf[g][kt] = *(const bf16x8*)(src + kt * 32 + kb0);
    }

    int qrow = quad & 1, rhalf = quad >> 1;
    int sp[2], bs[2]; float c[2];
    #pragma unroll
    for (int j = 0; j < 2; ++j) {
        sp[j] = qrow * 4 + rhalf * 2 + j;     // sample-local 0..7
        bs[j] = group * 8 + sp[j];
        c[j] = (s0 > 0) ? cb[(size_t)bs[j] * K + col] : 0.f;
    }
    int lastb[2] = { -1, -1 };
    float bngv = 0.f, bnbv = 0.f;
    if (OUTY) {
        bool is64 = (lastidx[1] | lastidx[3] | lastidx[5] | lastidx[7] |
                     lastidx[9] | lastidx[11] | lastidx[13] | lastidx[15]) == 0;
        lastb[0] = is64 ? lastidx[2 * bs[0]] : lastidx[bs[0]];
        lastb[1] = is64 ? lastidx[2 * bs[1]] : lastidx[bs[1]];
        bngv = bng[col] * rsqrtf(1.0f + 1e-5f);
        bnbv = bnb[col];
    }

    // prefetch xg for the first step
    float xv[2][4];
    #pragma unroll
    for (int j = 0; j < 2; ++j) {
        const float* xp = xg + ((size_t)bs[j]) * N4 + col;
        #pragma unroll
        for (int g = 0; g < 4; ++g) xv[j][g] = xp[g * 256];
    }

    for (int t = s0; t < s1; ++t) {
        // issue next-step xg loads early
        float xn[2][4];
        {
            int tn = (t + 1 < s1) ? (t + 1) : t;
            int xr = tn - s0;
            #pragma unroll
            for (int j = 0; j < 2; ++j) {
                const float* xp = xg + ((size_t)(xr * 256 + bs[j])) * N4 + col;
                #pragma unroll
                for (int g = 0; g < 4; ++g) xn[j][g] = xp[g * 256];
            }
        }
        f32x4 acc[4];
        if (t > 0) {
            u64* hsrc = hbg + (size_t)(t & 1) * (MB * K);
            u64 v[CNT];
            #pragma unroll
            for (int i = 0; i < CNT; ++i)
                v[i] = __hip_atomic_load(hsrc + tid + i * 256,
                                         __ATOMIC_RELAXED, __HIP_MEMORY_SCOPE_AGENT);
            for (;;) {
                bool ok = true;
                #pragma unroll
                for (int i = 0; i < CNT; ++i)
                    if ((unsigned int)(v[i] >> 32) != (unsigned int)t) ok = false;
                if (ok) break;
                __builtin_amdgcn_s_sleep(1);   // throttle spin
                #pragma unroll
                for (int i = 0; i < CNT; ++i)
                    if ((unsigned int)(v[i] >> 32) != (unsigned int)t)
                        v[i] = __hip_atomic_load(hsrc + tid + i * 256,
                                                 __ATOMIC_RELAXED, __HIP_MEMORY_SCOPE_AGENT);
            }
            // stage: word idx = tid + i*256 -> sample i, col tid
            #pragma unroll
            for (int i = 0; i < CNT; ++i) {
                unsigned int d = (unsigned int)v[i];
                Al[i][tid]     = (u16)(d & 0xffffu);
                Al[8 + i][tid] = (u16)(d >> 16);
            }
            __syncthreads();
            #pragma unroll
            for (int g = 0; g < 4; ++g) acc[g] = (f32x4){0.f, 0.f, 0.f, 0.f};
            #pragma unroll
            for (int kt = 0; kt < 8; ++kt) {
                bf16x8 a = *(const bf16x8*)&Al[fr_][kt * 32 + kb0];
                #pragma unroll
                for (int g = 0; g < 4; ++g) acc[g] = mfma16(a, bf[g][kt], acc[g]);
            }
            // combine hi (quads 0,1) + lo (quads 2,3): UNIFORM indices only
            #pragma unroll
            for (int g = 0; g < 4; ++g)
                #pragma unroll
                for (int rr = 0; rr < 4; ++rr)
                    acc[g][rr] += __shfl_xor(acc[g][rr], 32);
        }
        #pragma unroll
        for (int j = 0; j < 2; ++j) {
            float gg[4];
            #pragma unroll
            for (int g = 0; g < 4; ++g) {
                float pv = (t > 0) ? (rhalf ? acc[g][2 + j] : acc[g][j]) : 0.f;
                gg[g] = xv[j][g] + pv;
            }
            c[j] = fsig(gg[1]) * c[j] + fsig(gg[0]) * ftanh(gg[2]);
            float h = fsig(gg[3]) * ftanh(c[j]);
            u16 hh = f2bf(h);
            u16 hl = f2bf(h - bf2f(hh));
            u64 word = (u64)((unsigned int)hh | ((unsigned int)hl << 16))
                     | ((u64)(unsigned int)(t + 1) << 32);
            __hip_atomic_store(hbg + (size_t)((t + 1) & 1) * (MB * K) + (size_t)sp[j] * K + col,
                               word, __ATOMIC_RELAXED, __HIP_MEMORY_SCOPE_AGENT);
            if (OUTY == 0) {
                xoutc[((size_t)(t - s0) * 256 + bs[j]) * 256 + col] = h;
            } else if (t == lastb[j]) {
                float y = h * bngv + bnbv;
                y = y > 0.f ? y : 0.f;
                yout[(size_t)bs[j] * 256 + col] = y;
            }
        }
        #pragma unroll
        for (int j = 0; j < 2; ++j)
            #pragma unroll
            for (int g = 0; g < 4; ++g) xv[j][g] = xn[j][g];
    }
    #pragma unroll
    for (int j = 0; j < 2; ++j) cb[(size_t)bs[j] * K + col] = c[j];
}

// ---------------------------------------------------------------------------
// Fused stage-1 launch: blocks [0,64) recur1(chunk i-1), [64,2112) xg_fr(chunk i).
// ---------------------------------------------------------------------------
__global__ __launch_bounds__(256) void fused1_kernel(
    const float* __restrict__ embed,
    const u16* __restrict__ Wf16, const float* __restrict__ bfb,
    const u16* __restrict__ Wr16, const float* __restrict__ brb,
    float* __restrict__ xgfw, float* __restrict__ xgrw, int t0f, int t0r, int gon,
    const float* __restrict__ xgfr, const float* __restrict__ xgrr,
    const u16* __restrict__ whf16, const u16* __restrict__ whr16,
    float* __restrict__ cbf, float* __restrict__ cbr,
    float* __restrict__ hpf, float* __restrict__ hpr,
    float* __restrict__ X1, int s0, int s1, int ron)
{
    __shared__ SMemU sm;
    int b = blockIdx.x;
    if (b < 64) {
        if (ron)
            recur1_body(&sm, b, xgfr, xgrr, whf16, whr16, cbf, cbr, hpf, hpr, X1, s0, s1);
    } else {
        if (gon) {
            int idx = b - 64;
            xg_fr_body(&sm, idx & 7, idx >> 3, 256, embed, Wf16, bfb, Wr16, brb,
                       xgfw, xgrw, t0f, t0r);
        }
    }
}

// ---------------------------------------------------------------------------
// Fused stage-2/3 slot launch:
//  [0,256)    chain blocks, SAME-XCD GROUP MAPPING: x=b&7 (likely XCD),
//             k=b>>3; k<16 -> layer-2 chain, k>=16 -> layer-3 chain.
//             Within a chain: group = x*4 + (k&15)>>2, cw = k&3 — the 4
//             blocks of a group are b = x+8*(4q..4q+3), all on XCD x.
//  [256,768)  lean xg layer-1 chunk i+1  (64x128 tiles) -> G2[(i+1)&1]
//  [768,1280) xg layer-2 (+res+ln2) chunk i-1 (64x128)  -> G3[(i-1)&1]
// ---------------------------------------------------------------------------
__global__ __launch_bounds__(256) void fused2_kernel(
    const float* __restrict__ xg2, const u16* __restrict__ wh1,
    float* __restrict__ cb1, u64* hb1, float* __restrict__ Rw,
    int s2a, int s2b, int s2on,
    const float* __restrict__ xg3, const u16* __restrict__ wh2,
    float* __restrict__ cb2, u64* hb2, float* __restrict__ yout,
    const int* __restrict__ lastidx, const float* __restrict__ bng,
    const float* __restrict__ bnb, int s3a, int s3b, int s3on,
    const u16* __restrict__ X1p, const u16* __restrict__ w1p,
    const float* __restrict__ b1, float* __restrict__ G2w, int g2t0, int g2on,
    const float* __restrict__ Rr, const float* __restrict__ ln2g,
    const float* __restrict__ ln2b, const u16* __restrict__ w2p,
    const float* __restrict__ b2v, float* __restrict__ G3w, int g3t0, int g3on)
{
    __shared__ SMemU sm;
    int b = blockIdx.x;
    if (b < 256) {
        int x = b & 7, k = b >> 3;
        int sub = k & 15;
        int gid = (x * 4 + (sub >> 2)) * 4 + (sub & 3);   // group*4 + cw
        if (k < 16) {
            if (s2on)
                recur2_body<0>(&sm, gid, xg2, wh1, cb1, hb1, Rw,
                               nullptr, nullptr, nullptr, nullptr, s2a, s2b);
        } else {
            if (s3on)
                recur2_body<1>(&sm, gid, xg3, wh2, cb2, hb2,
                               nullptr, yout, lastidx, bng, bnb, s3a, s3b);
        }
    } else if (b < 768) {
        if (g2on) {
            int i = b - 256;
            xg_l16_body(&sm, i & 7, i >> 3, X1p, w1p, b1, G2w, g2t0);
        }
    } else {
        if (g3on) {
            int i = b - 768;
            xg_ln3_body(&sm, i & 7, i >> 3, X1p, Rr, ln2g, ln2b, w2p, b2v, G3w, g3t0);
        }
    }
}

// standalone lean layer-2 xg GEMM for chunk 0 (after prep_x1)
__global__ __launch_bounds__(256) void xg2_kernel(
    const u16* __restrict__ X1p, const u16* __restrict__ Wp,
    const float* __restrict__ bias, float* __restrict__ out, int t0)
{
    __shared__ SMemU sm;
    xg_l16_body(&sm, blockIdx.x, blockIdx.y, X1p, Wp, bias, out, t0);
}

// ---------------------------------------------------------------------------
// Launch
// ---------------------------------------------------------------------------
extern "C" void kernel_launch(void* const* d_in, const int* in_sizes, int n_in,
                              void* d_out, int out_size, void* d_ws, size_t ws_size,
                              hipStream_t stream)
{
    (void)in_sizes; (void)n_in; (void)out_size; (void)ws_size;
    const float* embed = (const float*)d_in[0];
    const int* lastidx = (const int*)d_in[1];
    const float* Wih_f = (const float*)d_in[2];
    const float* Whh_f = (const float*)d_in[3];
    const float* b_f   = (const float*)d_in[4];
    const float* Wih_r = (const float*)d_in[5];
    const float* Whh_r = (const float*)d_in[6];
    const float* b_r   = (const float*)d_in[7];
    const float* ln1g  = (const float*)d_in[8];
    const float* ln1b  = (const float*)d_in[9];
    const float* W1ih  = (const float*)d_in[10];
    const float* W1hh  = (const float*)d_in[11];
    const float* b1    = (const float*)d_in[12];
    const float* ln2g  = (const float*)d_in[13];
    const float* ln2b  = (const float*)d_in[14];
    const float* W2ih  = (const float*)d_in[15];
    const float* W2hh  = (const float*)d_in[16];
    const float* b2    = (const float*)d_in[17];
    const float* bng   = (const float*)d_in[18];
    const float* bnb   = (const float*)d_in[19];

    const size_t MiB = 1024 * 1024;
    char* ws = (char*)d_ws;
    float* G2[2] = { (float*)ws,               (float*)(ws + 16 * MiB) };
    float* G3[2] = { (float*)(ws + 32 * MiB),  (float*)(ws + 48 * MiB) };
    float* X1    =   (float*)(ws + 64 * MiB);   // 64 MiB; ln1 bf16 planes in place after prep
    float* R[2]  = { (float*)(ws + 128 * MiB), (float*)(ws + 132 * MiB) };  // 4 MiB each
    char* p = ws + 136 * MiB;
    u64* hb1 = (u64*)p;                         p += 1024 * 1024;
    u64* hb2 = (u64*)p;                         p += 1024 * 1024;
    float* cbf = (float*)p;                     p += 128 * 1024;
    float* cbr = (float*)p;                     p += 128 * 1024;
    float* cb1 = (float*)p;                     p += 256 * 1024;
    float* cb2 = (float*)p;                     p += 256 * 1024;
    float* hpf = (float*)p;                     p += 128 * 1024;
    float* hpr = (float*)p;                     p += 128 * 1024;
    u16* w1p   = (u16*)p;                       p += 512 * 1024;   // W1ih bf16 [1024][256]
    u16* w2p   = (u16*)p;                       p += 512 * 1024;   // W2ih bf16
    u16* wfp   = (u16*)p;                       p += 128 * 1024;   // Wih_f bf16 [512][128]
    u16* wrp   = (u16*)p;                       p += 128 * 1024;   // Wih_r bf16
    u16* wh1p  = (u16*)p;                       p += 512 * 1024;   // W1hh bf16
    u16* wh2p  = (u16*)p;                       p += 512 * 1024;   // W2hh bf16
    u16* whfp  = (u16*)p;                       p += 128 * 1024;   // Whh_f bf16
    u16* whrp  = (u16*)p;                       // Whh_r bf16

    const int CH1 = 32, n1 = 8;    // stage-1 chunking
    const int CH  = 16, n2 = 16;   // stage-2/3 chunking

    // one-time weight conversions (2 launches, 4 arrays each)
    prep_w4_kernel<<<2560, 256, 0, stream>>>(
        W1ih, w1p, 1024, W2ih, w2p, 1024, Wih_f, wfp, 256, Wih_r, wrp);
    prep_w4_kernel<<<2560, 256, 0, stream>>>(
        W1hh, wh1p, 1024, W2hh, wh2p, 1024, Whh_f, whfp, 256, Whh_r, whrp);

    // stage 1: bidirectional H=128 LSTM -> X1 (raw concat)
    for (int i = 0; i <= n1; ++i) {
        int gon = (i < n1), ron = (i >= 1);
        float* wf = (i & 1) ? G3[0] : G2[0];
        float* wr = (i & 1) ? G3[1] : G2[1];
        const float* rf = ((i - 1) & 1) ? G3[0] : G2[0];
        const float* rr_ = ((i - 1) & 1) ? G3[1] : G2[1];
        fused1_kernel<<<2112, 256, 0, stream>>>(
            embed, wfp, b_f, wrp, b_r, wf, wr, CH1 * i, 256 - CH1 * (i + 1), gon,
            rf, rr_, whfp, whrp, cbf, cbr, hpf, hpr, X1, CH1 * (i - 1), CH1 * i, ron);
    }

    // ln1 + bf16 hi/lo split, in place over X1
    prep_x1_kernel<<<16384, 256, 0, stream>>>(X1, ln1g, ln1b);
    const u16* X1p = (const u16*)X1;

    // stages 2+3, deep pipeline
    xg2_kernel<<<dim3(8, CH * 4), 256, 0, stream>>>(X1p, w1p, b1, G2[0], 0);
    for (int i = 0; i <= n2 + 1; ++i) {
        int s2on = (i < n2), s3on = (i >= 2);
        int g2on = (i + 1 < n2), g3on = (i >= 1 && i <= n2);
        fused2_kernel<<<1280, 256, 0, stream>>>(
            G2[i & 1], wh1p, cb1, hb1, R[i & 1], CH * i, CH * (i + 1), s2on,
            G3[(i - 2) & 1], wh2p, cb2, hb2, (float*)d_out, lastidx, bng, bnb,
            CH * (i - 2), CH * (i - 1), s3on,
            X1p, w1p, b1, G2[(i + 1) & 1], CH * (i + 1), g2on,
            R[(i - 1) & 1], ln2g, ln2b, w2p, b2, G3[(i - 1) & 1], CH * (i - 1), g3on);
    }
}

// Round 6
// 1885.624 us; speedup vs baseline: 1.9694x; 1.0590x over previous
//
#include <hip/hip_runtime.h>
#include <cstdint>
#include <cstddef>

typedef unsigned short u16;
typedef unsigned long long u64;
typedef __attribute__((ext_vector_type(8))) short bf16x8;  // 8 x bf16 (4 VGPRs)
typedef __attribute__((ext_vector_type(4))) float f32x4;
typedef __attribute__((ext_vector_type(4))) unsigned short u16x4;

#define DEV __device__ __forceinline__

DEV float bf2f(u16 h) { union { unsigned int u; float f; } x; x.u = ((unsigned int)h) << 16; return x.f; }
DEV u16 f2bf(float f) {
    union { float f; unsigned int u; } x; x.f = f;
    unsigned int u = x.u;
    return (u16)((u + 0x7fffu + ((u >> 16) & 1u)) >> 16);   // RNE
}
// fast gate math: __expf + v_rcp_f32; rel err ~1e-6 << bf16 weight rounding
DEV float fsig(float x)  { float e = __expf(-x);      return __builtin_amdgcn_rcpf(1.0f + e); }
DEV float ftanh(float x) { float e = __expf(2.0f * x); return 1.0f - 2.0f * __builtin_amdgcn_rcpf(e + 1.0f); }
DEV f32x4 mfma16(bf16x8 a, bf16x8 b, f32x4 c) {
    return __builtin_amdgcn_mfma_f32_16x16x32_bf16(a, b, c, 0, 0, 0);
}

// B=256, T=256, E=128, H=128 (per direction), H2=256. ALL tensors fp32.
//
// r14 (round 6): r5 post-mortem — slot 86us = ~16 chain steps + ~24us GEMM
// churn window; GEMM region loses ~14% to LDS bank conflicts (Bs stride 80B,
// 4-way) and re-stages W twice (hi/lo kt split re-reads same B slice).
// Changes (GEMM only; chain + exchange mapping verbatim from r5):
//  - xg_l16: 64x256 tile, B staged ONCE per K-slice, both A-planes (hi+lo)
//    run against it -> 32 MFMA/wave per barrier pair; 256 blocks/chunk.
//  - xg_ln3: 64x128 double-A same idea -> 16 MFMA/wave; 512 blocks/chunk.
//  - XOR granule swizzle (g ^= (row>>3)&3) on Bs write+read: kills the
//    4/8-way bank conflicts (verified bijective per 4-granule row).

union __align__(16) SMemU {
    struct { u16 As[2][64][40]; u16 Bs[256][40]; } g;   // 10240 + 20480 = 30720 B
    struct { u16 Al[2][16][136]; } r1;                  // recur1 h dbuf (8704 B)
    struct { u16 Al[16][264]; } r2;                     // recur2 h stage (8448 B)
};

// ---------------------------------------------------------------------------
// prep: fp32 -> bf16 conversion for 4 arrays in one launch (counts in
// 256-element blocks; all sizes here are multiples of 256)
// ---------------------------------------------------------------------------
__global__ __launch_bounds__(256) void prep_w4_kernel(
    const float* __restrict__ a0, u16* __restrict__ o0, int c0,
    const float* __restrict__ a1, u16* __restrict__ o1, int c1,
    const float* __restrict__ a2, u16* __restrict__ o2, int c2,
    const float* __restrict__ a3, u16* __restrict__ o3)
{
    int blk = blockIdx.x;
    const float* a; u16* o; int off;
    if (blk < c0)                { a = a0; o = o0; off = blk; }
    else if (blk < c0 + c1)      { a = a1; o = o1; off = blk - c0; }
    else if (blk < c0 + c1 + c2) { a = a2; o = o2; off = blk - c0 - c1; }
    else                         { a = a3; o = o3; off = blk - c0 - c1 - c2; }
    int i = off * 256 + threadIdx.x;
    o[i] = f2bf(a[i]);
}

// ---------------------------------------------------------------------------
// prep: ln1 over X1 rows, store bf16 hi/lo planes IN PLACE over the row.
// Row r (1KB): bytes [0,512) = H plane u16[256], [512,1024) = L plane.
// ---------------------------------------------------------------------------
__global__ __launch_bounds__(256) void prep_x1_kernel(
    float* __restrict__ X, const float* __restrict__ gw, const float* __restrict__ bw)
{
    int row  = blockIdx.x * 4 + (threadIdx.x >> 6);
    int lane = threadIdx.x & 63;
    float* xr = X + (size_t)row * 256;
    f32x4 v = *(const f32x4*)(xr + lane * 4);
    float s = v[0] + v[1] + v[2] + v[3];
    #pragma unroll
    for (int mm = 1; mm < 64; mm <<= 1) s += __shfl_xor(s, mm, 64);
    float mu = s * (1.0f / 256.0f);
    f32x4 e = v - mu;
    float q = e[0]*e[0] + e[1]*e[1] + e[2]*e[2] + e[3]*e[3];
    #pragma unroll
    for (int mm = 1; mm < 64; mm <<= 1) q += __shfl_xor(q, mm, 64);
    float rs = rsqrtf(q * (1.0f / 256.0f) + 1e-5f);
    int c0 = lane * 4;
    u16x4 hv, lv;
    #pragma unroll
    for (int i = 0; i < 4; ++i) {
        float o = e[i] * rs * gw[c0 + i] + bw[c0 + i];
        u16 hh = f2bf(o);
        hv[i] = hh;
        lv[i] = f2bf(o - bf2f(hh));
    }
    u16* H = (u16*)xr;
    *(u16x4*)(H + lane * 4)       = hv;
    *(u16x4*)(H + 256 + lane * 4) = lv;
}

// ---------------------------------------------------------------------------
// xg GEMM body, first (bi) layer. A = embed fp32 (split on the fly),
// W = pre-converted bf16. 64x64 tile (K=128 layer; As/Bs indexing 2-way free).
// ---------------------------------------------------------------------------
DEV void xg_fr_body(SMemU* smu, int bx, int by, int nby,
    const float* __restrict__ embed,
    const u16* __restrict__ Wf16, const float* __restrict__ bf_,
    const u16* __restrict__ Wr16, const float* __restrict__ br_,
    float* __restrict__ xgf, float* __restrict__ xgr, int t0f, int t0r)
{
    auto& As = smu->g.As[0];
    auto& Bs = smu->g.Bs;
    int tid = threadIdx.x;
    int half = nby >> 1;
    bool isR = by >= half;
    int m0 = (by - (isR ? half : 0)) * 64;
    const u16* W      = isR ? Wr16 : Wf16;
    const float* bias = isR ? br_ : bf_;
    float* out        = isR ? xgr : xgf;
    int tbase         = isR ? t0r : t0f;
    int n0 = bx * 64;

    int r  = tid >> 2;
    int kc = (tid & 3) * 8;
    int m  = m0 + r;
    int tl = m >> 8, bb = m & 255;
    const float* arow = embed + ((size_t)(bb * 256 + (tbase + tl)) * 128);
    const u16* brow = W + ((size_t)(n0 + r) * 128);

    f32x4 acc[4];
    #pragma unroll
    for (int i = 0; i < 4; ++i) acc[i] = (f32x4){0.f, 0.f, 0.f, 0.f};
    int lane = tid & 63, w = tid >> 6;
    int fr_ = lane & 15, kb0 = (lane >> 4) * 8;

    for (int kt = 0; kt < 8; ++kt) {
        int sc = (kt & 3) * 32 + kc;
        bool lo = kt >= 4;
        f32x4 va = *(const f32x4*)(arow + sc);
        f32x4 vb = *(const f32x4*)(arow + sc + 4);
        bf16x8 wv = *(const bf16x8*)(brow + sc);
        bf16x8 hv;
        #pragma unroll
        for (int i = 0; i < 8; ++i) {
            float v = (i < 4) ? va[i] : vb[i - 4];
            u16 hi = f2bf(v);
            hv[i] = (short)(lo ? f2bf(v - bf2f(hi)) : hi);
        }
        *(bf16x8*)&As[r][kc] = hv;
        *(bf16x8*)&Bs[r][kc] = wv;
        __syncthreads();
        bf16x8 bfrg = *(const bf16x8*)&Bs[w * 16 + fr_][kb0];
        #pragma unroll
        for (int mt = 0; mt < 4; ++mt) {
            bf16x8 afrg = *(const bf16x8*)&As[mt * 16 + fr_][kb0];
            acc[mt] = mfma16(afrg, bfrg, acc[mt]);
        }
        __syncthreads();
    }
    int col = n0 + w * 16 + fr_;
    float bvv = bias[col];
    int rq = (lane >> 4) * 4;
    #pragma unroll
    for (int mt = 0; mt < 4; ++mt)
        #pragma unroll
        for (int rr = 0; rr < 4; ++rr) {
            int mrow = m0 + mt * 16 + rq + rr;
            out[(size_t)mrow * 512 + col] = acc[mt][rr] + bvv;
        }
}

// ---------------------------------------------------------------------------
// LEAN layer-2 xg GEMM, 64x256 tile. Per K-slice (8 iters): B (256 rows x 32)
// staged ONCE (swizzled granules), both A planes (hi+lo) staged, 32 MFMA/wave.
// ---------------------------------------------------------------------------
DEV void xg_l16_body(SMemU* smu, int bx, int by,
    const u16* __restrict__ X1p, const u16* __restrict__ Wp,
    const float* __restrict__ bias, float* __restrict__ out, int t0)
{
    auto& As = smu->g.As;       // [2][64][40]
    auto& Bs = smu->g.Bs;       // [256][40]
    int tid = threadIdx.x;
    int m0 = by * 64, n0 = bx * 256;
    int rA = tid >> 2, kcA = (tid & 3) * 8;
    int m  = m0 + rA;
    int tl = m >> 8, bb = m & 255;
    const u16* arow = X1p + ((size_t)((t0 + tl) * 256 + bb)) * 512;  // H then L plane
    const u16* brow = Wp + ((size_t)(n0 + tid)) * 256;
    int swB = (tid >> 3) & 3;    // write-side granule swizzle for row = tid

    f32x4 acc[4][4];
    #pragma unroll
    for (int cs = 0; cs < 4; ++cs)
        #pragma unroll
        for (int i = 0; i < 4; ++i) acc[cs][i] = (f32x4){0.f, 0.f, 0.f, 0.f};
    int lane = tid & 63, w = tid >> 6;
    int fr_ = lane & 15, quad = lane >> 4, kb0 = quad * 8;

    for (int kt = 0; kt < 8; ++kt) {
        int sc = kt * 32;
        bf16x8 hvH = *(const bf16x8*)(arow + sc + kcA);
        bf16x8 hvL = *(const bf16x8*)(arow + 256 + sc + kcA);
        bf16x8 wv0 = *(const bf16x8*)(brow + sc);
        bf16x8 wv1 = *(const bf16x8*)(brow + sc + 8);
        bf16x8 wv2 = *(const bf16x8*)(brow + sc + 16);
        bf16x8 wv3 = *(const bf16x8*)(brow + sc + 24);
        *(bf16x8*)&As[0][rA][kcA] = hvH;
        *(bf16x8*)&As[1][rA][kcA] = hvL;
        *(bf16x8*)&Bs[tid][(0 ^ swB) * 8] = wv0;
        *(bf16x8*)&Bs[tid][(1 ^ swB) * 8] = wv1;
        *(bf16x8*)&Bs[tid][(2 ^ swB) * 8] = wv2;
        *(bf16x8*)&Bs[tid][(3 ^ swB) * 8] = wv3;
        __syncthreads();
        bf16x8 bfrg[4];
        #pragma unroll
        for (int cs = 0; cs < 4; ++cs) {
            int Br = cs * 64 + w * 16 + fr_;
            int g  = quad ^ ((Br >> 3) & 3);
            bfrg[cs] = *(const bf16x8*)&Bs[Br][g * 8];
        }
        #pragma unroll
        for (int h = 0; h < 2; ++h)
            #pragma unroll
            for (int mt = 0; mt < 4; ++mt) {
                bf16x8 afrg = *(const bf16x8*)&As[h][mt * 16 + fr_][kb0];
                #pragma unroll
                for (int cs = 0; cs < 4; ++cs)
                    acc[cs][mt] = mfma16(afrg, bfrg[cs], acc[cs][mt]);
            }
        __syncthreads();
    }
    int rq = (lane >> 4) * 4;
    #pragma unroll
    for (int cs = 0; cs < 4; ++cs) {
        int col = n0 + cs * 64 + w * 16 + fr_;
        float bvv = bias[col];
        #pragma unroll
        for (int mt = 0; mt < 4; ++mt)
            #pragma unroll
            for (int rr = 0; rr < 4; ++rr) {
                int mrow = m0 + mt * 16 + rq + rr;
                out[(size_t)mrow * 1024 + col] = acc[cs][mt][rr] + bvv;
            }
    }
}

// ---------------------------------------------------------------------------
// layer-3 xg GEMM, 64x128 tile, double-A: A = ln2( R + (H+L of ln1X1) ).
// B staged once per K-slice (swizzled), hi+lo A planes -> 16 MFMA/wave.
// ---------------------------------------------------------------------------
DEV void xg_ln3_body(SMemU* smu, int bx, int by,
    const u16* __restrict__ X1p, const float* __restrict__ Rc,
    const float* __restrict__ l2g, const float* __restrict__ l2b,
    const u16* __restrict__ Wp, const float* __restrict__ bias,
    float* __restrict__ out, int t0)
{
    auto& As = smu->g.As;       // [2][64][40]
    auto& Bs = smu->g.Bs;       // use rows [0,128)
    int tid = threadIdx.x;
    int m0 = by * 64, n0 = bx * 128;
    int rA = tid >> 2, kcA = (tid & 3) * 8;
    int rB = tid >> 1, cB = tid & 1;
    int m  = m0 + rA;
    int tl = m >> 8, bb = m & 255;
    const u16* a1 = X1p + ((size_t)((t0 + tl) * 256 + bb)) * 512;
    const float* a2 = Rc + ((size_t)(tl * 256 + bb)) * 256;
    const u16* brow = Wp + ((size_t)(n0 + rB)) * 256;
    int swB = (rB >> 3) & 3;

    float xc[8][8];
    float s = 0.f;
    #pragma unroll
    for (int q = 0; q < 8; ++q) {
        int sc = q * 32 + kcA;
        bf16x8 hx = *(const bf16x8*)(a1 + sc);
        bf16x8 lx = *(const bf16x8*)(a1 + 256 + sc);
        f32x4 u2 = *(const f32x4*)(a2 + sc);
        f32x4 v2 = *(const f32x4*)(a2 + sc + 4);
        #pragma unroll
        for (int i = 0; i < 8; ++i) {
            float rv = (i < 4) ? u2[i] : v2[i - 4];
            xc[q][i] = bf2f((u16)hx[i]) + bf2f((u16)lx[i]) + rv;
            s += xc[q][i];
        }
    }
    s += __shfl_xor(s, 1); s += __shfl_xor(s, 2);
    float mu = s * (1.0f / 256.0f);
    float q2 = 0.f;
    #pragma unroll
    for (int q = 0; q < 8; ++q)
        #pragma unroll
        for (int i = 0; i < 8; ++i) { float e = xc[q][i] - mu; q2 += e * e; }
    q2 += __shfl_xor(q2, 1); q2 += __shfl_xor(q2, 2);
    float rs = rsqrtf(q2 * (1.0f / 256.0f) + 1e-5f);
    #pragma unroll
    for (int q = 0; q < 8; ++q) {
        int sc = q * 32 + kcA;
        f32x4 g1 = *(const f32x4*)(l2g + sc);
        f32x4 g2v = *(const f32x4*)(l2g + sc + 4);
        f32x4 h1 = *(const f32x4*)(l2b + sc);
        f32x4 h2 = *(const f32x4*)(l2b + sc + 4);
        #pragma unroll
        for (int i = 0; i < 4; ++i) {
            xc[q][i]     = (xc[q][i]     - mu) * rs * g1[i]  + h1[i];
            xc[q][4 + i] = (xc[q][4 + i] - mu) * rs * g2v[i] + h2[i];
        }
    }

    f32x4 acc[2][4];
    #pragma unroll
    for (int cs = 0; cs < 2; ++cs)
        #pragma unroll
        for (int i = 0; i < 4; ++i) acc[cs][i] = (f32x4){0.f, 0.f, 0.f, 0.f};
    int lane = tid & 63, w = tid >> 6;
    int fr_ = lane & 15, quad = lane >> 4, kb0 = quad * 8;

    #pragma unroll        // xc must be statically indexed (no scratch)
    for (int kt = 0; kt < 8; ++kt) {
        int sc = kt * 32;
        bf16x8 wv0 = *(const bf16x8*)(brow + sc + cB * 16);
        bf16x8 wv1 = *(const bf16x8*)(brow + sc + cB * 16 + 8);
        bf16x8 hvH, hvL;
        #pragma unroll
        for (int i = 0; i < 8; ++i) {
            float v = xc[kt][i];
            u16 hi = f2bf(v);
            hvH[i] = (short)hi;
            hvL[i] = (short)f2bf(v - bf2f(hi));
        }
        *(bf16x8*)&As[0][rA][kcA] = hvH;
        *(bf16x8*)&As[1][rA][kcA] = hvL;
        *(bf16x8*)&Bs[rB][((2 * cB) ^ swB) * 8]     = wv0;
        *(bf16x8*)&Bs[rB][((2 * cB + 1) ^ swB) * 8] = wv1;
        __syncthreads();
        bf16x8 bfrg[2];
        #pragma unroll
        for (int cs = 0; cs < 2; ++cs) {
            int Br = cs * 64 + w * 16 + fr_;
            int g  = quad ^ ((Br >> 3) & 3);
            bfrg[cs] = *(const bf16x8*)&Bs[Br][g * 8];
        }
        #pragma unroll
        for (int h = 0; h < 2; ++h)
            #pragma unroll
            for (int mt = 0; mt < 4; ++mt) {
                bf16x8 afrg = *(const bf16x8*)&As[h][mt * 16 + fr_][kb0];
                #pragma unroll
                for (int cs = 0; cs < 2; ++cs)
                    acc[cs][mt] = mfma16(afrg, bfrg[cs], acc[cs][mt]);
            }
        __syncthreads();
    }
    int rq = (lane >> 4) * 4;
    #pragma unroll
    for (int cs = 0; cs < 2; ++cs) {
        int col = n0 + cs * 64 + w * 16 + fr_;
        float bvv = bias[col];
        #pragma unroll
        for (int mt = 0; mt < 4; ++mt)
            #pragma unroll
            for (int rr = 0; rr < 4; ++rr) {
                int mrow = m0 + mt * 16 + rq + rr;
                out[(size_t)mrow * 1024 + col] = acc[cs][mt][rr] + bvv;
            }
    }
}

// ---------------------------------------------------------------------------
// Stage-1 recurrence body (H=128). One barrier per step, C-domain gate
// fusion, hi/lo h in LDS dbuf, next-step xg prefetch. Whh pre-converted bf16.
// ---------------------------------------------------------------------------
DEV void recur1_body(SMemU* smu, int bid,
    const float* __restrict__ xgf, const float* __restrict__ xgr,
    const u16* __restrict__ whf16, const u16* __restrict__ whr16,
    float* __restrict__ cbf, float* __restrict__ cbr,
    float* __restrict__ hpf, float* __restrict__ hpr,
    float* __restrict__ xout, int s0, int s1)
{
    __builtin_amdgcn_s_setprio(1);
    constexpr int K = 128, N4 = 512;
    auto& Al = smu->r1.Al;

    int tid = threadIdx.x, lane = tid & 63, w = tid >> 6;
    int fr_ = lane & 15, quad = lane >> 4, kb0 = quad * 8;
    int dir = bid >> 5, gidx = bid & 31;
    const float* xg  = dir ? xgr  : xgf;
    const u16* whh16 = dir ? whr16 : whf16;
    float* cb = dir ? cbr : cbf;
    float* hp = dir ? hpr : hpf;
    int coloff = dir ? 128 : 0;

    bf16x8 bf[4][2][4];
    #pragma unroll
    for (int g = 0; g < 4; ++g)
        #pragma unroll
        for (int u = 0; u < 2; ++u) {
            const u16* src = whh16 + (size_t)(g * K + w * 32 + u * 16 + fr_) * K;
            #pragma unroll
            for (int kt = 0; kt < 4; ++kt)
                bf[g][u][kt] = *(const bf16x8*)(src + kt * 32 + kb0);
        }

    int uq = quad >> 1, qrow = quad & 1;
    int colw = w * 32 + uq * 16 + fr_;        // 0..127
    int b0 = gidx * 8;
    float c[4];
    #pragma unroll
    for (int rr = 0; rr < 4; ++rr)
        c[rr] = (s0 > 0) ? cb[(size_t)(b0 + qrow * 4 + rr) * K + colw] : 0.f;

    if (s0 > 0) {   // preload h (fp32) into Al[s0&1] hi/lo
        for (int idx = tid; idx < 8 * K; idx += 256) {
            int sa = idx >> 7, k = idx & 127;
            float v = hp[(size_t)(b0 + sa) * K + k];
            u16 hh = f2bf(v);
            Al[s0 & 1][sa][k] = hh;
            Al[s0 & 1][8 + sa][k] = f2bf(v - bf2f(hh));
        }
    }
    __syncthreads();

    // prefetch xg for the first step
    float xv[4][4];
    {
        int xrow = dir ? (s1 - 1 - s0) : 0;
        #pragma unroll
        for (int rr = 0; rr < 4; ++rr) {
            const float* xp = xg + ((size_t)(xrow * 256 + b0 + qrow * 4 + rr)) * N4 + colw;
            #pragma unroll
            for (int g = 0; g < 4; ++g) xv[rr][g] = xp[g * K];
        }
    }

    for (int t = s0; t < s1; ++t) {
        float xn[4][4];
        {
            int tn = (t + 1 < s1) ? (t + 1) : t;
            int xrow = dir ? (s1 - 1 - tn) : (tn - s0);
            #pragma unroll
            for (int rr = 0; rr < 4; ++rr) {
                const float* xp = xg + ((size_t)(xrow * 256 + b0 + qrow * 4 + rr)) * N4 + colw;
                #pragma unroll
                for (int g = 0; g < 4; ++g) xn[rr][g] = xp[g * K];
            }
        }
        f32x4 acc[4][2];
        if (t > 0) {
            #pragma unroll
            for (int g = 0; g < 4; ++g)
                #pragma unroll
                for (int u = 0; u < 2; ++u) acc[g][u] = (f32x4){0.f, 0.f, 0.f, 0.f};
            #pragma unroll
            for (int kt = 0; kt < 4; ++kt) {
                bf16x8 a = *(const bf16x8*)&Al[t & 1][fr_][kt * 32 + kb0];
                #pragma unroll
                for (int g = 0; g < 4; ++g)
                    #pragma unroll
                    for (int u = 0; u < 2; ++u) acc[g][u] = mfma16(a, bf[g][u][kt], acc[g][u]);
            }
            // combine hi (quads 0,1) + lo (quads 2,3): UNIFORM indices only
            #pragma unroll
            for (int g = 0; g < 4; ++g)
                #pragma unroll
                for (int u = 0; u < 2; ++u)
                    #pragma unroll
                    for (int rr = 0; rr < 4; ++rr)
                        acc[g][u][rr] += __shfl_xor(acc[g][u][rr], 32);
        }
        int tt = dir ? (255 - t) : t;
        #pragma unroll
        for (int rr = 0; rr < 4; ++rr) {
            int s = qrow * 4 + rr;
            float gg[4];
            #pragma unroll
            for (int g = 0; g < 4; ++g) {
                float pv = (t > 0) ? (uq ? acc[g][1][rr] : acc[g][0][rr]) : 0.f;
                gg[g] = xv[rr][g] + pv;
            }
            c[rr] = fsig(gg[1]) * c[rr] + fsig(gg[0]) * ftanh(gg[2]);
            float h = fsig(gg[3]) * ftanh(c[rr]);
            u16 hh = f2bf(h);
            Al[(t + 1) & 1][s][colw] = hh;
            Al[(t + 1) & 1][8 + s][colw] = f2bf(h - bf2f(hh));
            xout[((size_t)tt * 256 + b0 + s) * 256 + coloff + colw] = h;
            if (t == s1 - 1) hp[(size_t)(b0 + s) * K + colw] = h;
        }
        __syncthreads();
        #pragma unroll
        for (int rr = 0; rr < 4; ++rr)
            #pragma unroll
            for (int g = 0; g < 4; ++g) xv[rr][g] = xn[rr][g];
    }
    #pragma unroll
    for (int rr = 0; rr < 4; ++rr)
        cb[(size_t)(b0 + qrow * 4 + rr) * K + colw] = c[rr];
}

// ---------------------------------------------------------------------------
// H2 recurrence body (K=256). 64-bit tagged agent-atomic h exchange, one
// barrier/step, next-step xg prefetch, s_sleep-throttled spin. Whh bf16.
// OUTY 0: write h to chunk-local buffer. OUTY 1: write y at t==lastidx[b].
// ---------------------------------------------------------------------------
template<int OUTY>
DEV void recur2_body(SMemU* smu, int bid,
    const float* __restrict__ xg, const u16* __restrict__ whh16,
    float* __restrict__ cb, u64* hb,
    float* __restrict__ xoutc, float* __restrict__ yout,
    const int* __restrict__ lastidx,
    const float* __restrict__ bng, const float* __restrict__ bnb,
    int s0, int s1)
{
    __builtin_amdgcn_s_setprio(1);
    constexpr int K = 256, MB = 8, N4 = 1024;
    constexpr int CNT = MB * K / 256;   // 8 poll words per thread
    auto& Al = smu->r2.Al;

    int tid = threadIdx.x, lane = tid & 63, w = tid >> 6;
    int fr_ = lane & 15, quad = lane >> 4, kb0 = quad * 8;
    int group = bid >> 2, cw = bid & 3;
    u64* hbg = hb + (size_t)group * (2 * MB * K);
    int col = cw * 64 + w * 16 + fr_;         // 0..255

    bf16x8 bf[4][8];
    #pragma unroll
    for (int g = 0; g < 4; ++g) {
        const u16* src = whh16 + (size_t)(g * 256 + col) * K;
        #pragma unroll
        for (int kt = 0; kt < 8; ++kt)
            bf[g][kt] = *(const bf16x8*)(src + kt * 32 + kb0);
    }

    int qrow = quad & 1, rhalf = quad >> 1;
    int sp[2], bs[2]; float c[2];
    #pragma unroll
    for (int j = 0; j < 2; ++j) {
        sp[j] = qrow * 4 + rhalf * 2 + j;     // sample-local 0..7
        bs[j] = group * 8 + sp[j];
        c[j] = (s0 > 0) ? cb[(size_t)bs[j] * K + col] : 0.f;
    }
    int lastb[2] = { -1, -1 };
    float bngv = 0.f, bnbv = 0.f;
    if (OUTY) {
        bool is64 = (lastidx[1] | lastidx[3] | lastidx[5] | lastidx[7] |
                     lastidx[9] | lastidx[11] | lastidx[13] | lastidx[15]) == 0;
        lastb[0] = is64 ? lastidx[2 * bs[0]] : lastidx[bs[0]];
        lastb[1] = is64 ? lastidx[2 * bs[1]] : lastidx[bs[1]];
        bngv = bng[col] * rsqrtf(1.0f + 1e-5f);
        bnbv = bnb[col];
    }

    // prefetch xg for the first step
    float xv[2][4];
    #pragma unroll
    for (int j = 0; j < 2; ++j) {
        const float* xp = xg + ((size_t)bs[j]) * N4 + col;
        #pragma unroll
        for (int g = 0; g < 4; ++g) xv[j][g] = xp[g * 256];
    }

    for (int t = s0; t < s1; ++t) {
        // issue next-step xg loads early
        float xn[2][4];
        {
            int tn = (t + 1 < s1) ? (t + 1) : t;
            int xr = tn - s0;
            #pragma unroll
            for (int j = 0; j < 2; ++j) {
                const float* xp = xg + ((size_t)(xr * 256 + bs[j])) * N4 + col;
                #pragma unroll
                for (int g = 0; g < 4; ++g) xn[j][g] = xp[g * 256];
            }
        }
        f32x4 acc[4];
        if (t > 0) {
            u64* hsrc = hbg + (size_t)(t & 1) * (MB * K);
            u64 v[CNT];
            #pragma unroll
            for (int i = 0; i < CNT; ++i)
                v[i] = __hip_atomic_load(hsrc + tid + i * 256,
                                         __ATOMIC_RELAXED, __HIP_MEMORY_SCOPE_AGENT);
            for (;;) {
                bool ok = true;
                #pragma unroll
                for (int i = 0; i < CNT; ++i)
                    if ((unsigned int)(v[i] >> 32) != (unsigned int)t) ok = false;
                if (ok) break;
                __builtin_amdgcn_s_sleep(1);   // throttle spin
                #pragma unroll
                for (int i = 0; i < CNT; ++i)
                    if ((unsigned int)(v[i] >> 32) != (unsigned int)t)
                        v[i] = __hip_atomic_load(hsrc + tid + i * 256,
                                                 __ATOMIC_RELAXED, __HIP_MEMORY_SCOPE_AGENT);
            }
            // stage: word idx = tid + i*256 -> sample i, col tid
            #pragma unroll
            for (int i = 0; i < CNT; ++i) {
                unsigned int d = (unsigned int)v[i];
                Al[i][tid]     = (u16)(d & 0xffffu);
                Al[8 + i][tid] = (u16)(d >> 16);
            }
            __syncthreads();
            #pragma unroll
            for (int g = 0; g < 4; ++g) acc[g] = (f32x4){0.f, 0.f, 0.f, 0.f};
            #pragma unroll
            for (int kt = 0; kt < 8; ++kt) {
                bf16x8 a = *(const bf16x8*)&Al[fr_][kt * 32 + kb0];
                #pragma unroll
                for (int g = 0; g < 4; ++g) acc[g] = mfma16(a, bf[g][kt], acc[g]);
            }
            // combine hi (quads 0,1) + lo (quads 2,3): UNIFORM indices only
            #pragma unroll
            for (int g = 0; g < 4; ++g)
                #pragma unroll
                for (int rr = 0; rr < 4; ++rr)
                    acc[g][rr] += __shfl_xor(acc[g][rr], 32);
        }
        #pragma unroll
        for (int j = 0; j < 2; ++j) {
            float gg[4];
            #pragma unroll
            for (int g = 0; g < 4; ++g) {
                float pv = (t > 0) ? (rhalf ? acc[g][2 + j] : acc[g][j]) : 0.f;
                gg[g] = xv[j][g] + pv;
            }
            c[j] = fsig(gg[1]) * c[j] + fsig(gg[0]) * ftanh(gg[2]);
            float h = fsig(gg[3]) * ftanh(c[j]);
            u16 hh = f2bf(h);
            u16 hl = f2bf(h - bf2f(hh));
            u64 word = (u64)((unsigned int)hh | ((unsigned int)hl << 16))
                     | ((u64)(unsigned int)(t + 1) << 32);
            __hip_atomic_store(hbg + (size_t)((t + 1) & 1) * (MB * K) + (size_t)sp[j] * K + col,
                               word, __ATOMIC_RELAXED, __HIP_MEMORY_SCOPE_AGENT);
            if (OUTY == 0) {
                xoutc[((size_t)(t - s0) * 256 + bs[j]) * 256 + col] = h;
            } else if (t == lastb[j]) {
                float y = h * bngv + bnbv;
                y = y > 0.f ? y : 0.f;
                yout[(size_t)bs[j] * 256 + col] = y;
            }
        }
        #pragma unroll
        for (int j = 0; j < 2; ++j)
            #pragma unroll
            for (int g = 0; g < 4; ++g) xv[j][g] = xn[j][g];
    }
    #pragma unroll
    for (int j = 0; j < 2; ++j) cb[(size_t)bs[j] * K + col] = c[j];
}

// ---------------------------------------------------------------------------
// Fused stage-1 launch: blocks [0,64) recur1(chunk i-1), [64,2112) xg_fr(chunk i).
// ---------------------------------------------------------------------------
__global__ __launch_bounds__(256) void fused1_kernel(
    const float* __restrict__ embed,
    const u16* __restrict__ Wf16, const float* __restrict__ bfb,
    const u16* __restrict__ Wr16, const float* __restrict__ brb,
    float* __restrict__ xgfw, float* __restrict__ xgrw, int t0f, int t0r, int gon,
    const float* __restrict__ xgfr, const float* __restrict__ xgrr,
    const u16* __restrict__ whf16, const u16* __restrict__ whr16,
    float* __restrict__ cbf, float* __restrict__ cbr,
    float* __restrict__ hpf, float* __restrict__ hpr,
    float* __restrict__ X1, int s0, int s1, int ron)
{
    __shared__ SMemU sm;
    int b = blockIdx.x;
    if (b < 64) {
        if (ron)
            recur1_body(&sm, b, xgfr, xgrr, whf16, whr16, cbf, cbr, hpf, hpr, X1, s0, s1);
    } else {
        if (gon) {
            int idx = b - 64;
            xg_fr_body(&sm, idx & 7, idx >> 3, 256, embed, Wf16, bfb, Wr16, brb,
                       xgfw, xgrw, t0f, t0r);
        }
    }
}

// ---------------------------------------------------------------------------
// Fused stage-2/3 slot launch:
//  [0,256)     chain blocks, same-XCD group mapping (verbatim r5)
//  [256,512)   lean xg layer-1 chunk i+1, 64x256 tiles  -> G2[(i+1)&1]
//  [512,1024)  xg layer-2 (+res+ln2) chunk i-1, 64x128  -> G3[(i-1)&1]
// ---------------------------------------------------------------------------
__global__ __launch_bounds__(256) void fused2_kernel(
    const float* __restrict__ xg2, const u16* __restrict__ wh1,
    float* __restrict__ cb1, u64* hb1, float* __restrict__ Rw,
    int s2a, int s2b, int s2on,
    const float* __restrict__ xg3, const u16* __restrict__ wh2,
    float* __restrict__ cb2, u64* hb2, float* __restrict__ yout,
    const int* __restrict__ lastidx, const float* __restrict__ bng,
    const float* __restrict__ bnb, int s3a, int s3b, int s3on,
    const u16* __restrict__ X1p, const u16* __restrict__ w1p,
    const float* __restrict__ b1, float* __restrict__ G2w, int g2t0, int g2on,
    const float* __restrict__ Rr, const float* __restrict__ ln2g,
    const float* __restrict__ ln2b, const u16* __restrict__ w2p,
    const float* __restrict__ b2v, float* __restrict__ G3w, int g3t0, int g3on)
{
    __shared__ SMemU sm;
    int b = blockIdx.x;
    if (b < 256) {
        int x = b & 7, k = b >> 3;
        int sub = k & 15;
        int gid = (x * 4 + (sub >> 2)) * 4 + (sub & 3);   // group*4 + cw
        if (k < 16) {
            if (s2on)
                recur2_body<0>(&sm, gid, xg2, wh1, cb1, hb1, Rw,
                               nullptr, nullptr, nullptr, nullptr, s2a, s2b);
        } else {
            if (s3on)
                recur2_body<1>(&sm, gid, xg3, wh2, cb2, hb2,
                               nullptr, yout, lastidx, bng, bnb, s3a, s3b);
        }
    } else if (b < 512) {
        if (g2on) {
            int i = b - 256;                    // 0..255: bx 0..3, by 0..63
            xg_l16_body(&sm, i & 3, i >> 2, X1p, w1p, b1, G2w, g2t0);
        }
    } else {
        if (g3on) {
            int i = b - 512;                    // 0..511: bx 0..7, by 0..63
            xg_ln3_body(&sm, i & 7, i >> 3, X1p, Rr, ln2g, ln2b, w2p, b2v, G3w, g3t0);
        }
    }
}

// standalone lean layer-2 xg GEMM for chunk 0 (after prep_x1)
__global__ __launch_bounds__(256) void xg2_kernel(
    const u16* __restrict__ X1p, const u16* __restrict__ Wp,
    const float* __restrict__ bias, float* __restrict__ out, int t0)
{
    __shared__ SMemU sm;
    xg_l16_body(&sm, blockIdx.x, blockIdx.y, X1p, Wp, bias, out, t0);
}

// ---------------------------------------------------------------------------
// Launch
// ---------------------------------------------------------------------------
extern "C" void kernel_launch(void* const* d_in, const int* in_sizes, int n_in,
                              void* d_out, int out_size, void* d_ws, size_t ws_size,
                              hipStream_t stream)
{
    (void)in_sizes; (void)n_in; (void)out_size; (void)ws_size;
    const float* embed = (const float*)d_in[0];
    const int* lastidx = (const int*)d_in[1];
    const float* Wih_f = (const float*)d_in[2];
    const float* Whh_f = (const float*)d_in[3];
    const float* b_f   = (const float*)d_in[4];
    const float* Wih_r = (const float*)d_in[5];
    const float* Whh_r = (const float*)d_in[6];
    const float* b_r   = (const float*)d_in[7];
    const float* ln1g  = (const float*)d_in[8];
    const float* ln1b  = (const float*)d_in[9];
    const float* W1ih  = (const float*)d_in[10];
    const float* W1hh  = (const float*)d_in[11];
    const float* b1    = (const float*)d_in[12];
    const float* ln2g  = (const float*)d_in[13];
    const float* ln2b  = (const float*)d_in[14];
    const float* W2ih  = (const float*)d_in[15];
    const float* W2hh  = (const float*)d_in[16];
    const float* b2    = (const float*)d_in[17];
    const float* bng   = (const float*)d_in[18];
    const float* bnb   = (const float*)d_in[19];

    const size_t MiB = 1024 * 1024;
    char* ws = (char*)d_ws;
    float* G2[2] = { (float*)ws,               (float*)(ws + 16 * MiB) };
    float* G3[2] = { (float*)(ws + 32 * MiB),  (float*)(ws + 48 * MiB) };
    float* X1    =   (float*)(ws + 64 * MiB);   // 64 MiB; ln1 bf16 planes in place after prep
    float* R[2]  = { (float*)(ws + 128 * MiB), (float*)(ws + 132 * MiB) };  // 4 MiB each
    char* p = ws + 136 * MiB;
    u64* hb1 = (u64*)p;                         p += 1024 * 1024;
    u64* hb2 = (u64*)p;                         p += 1024 * 1024;
    float* cbf = (float*)p;                     p += 128 * 1024;
    float* cbr = (float*)p;                     p += 128 * 1024;
    float* cb1 = (float*)p;                     p += 256 * 1024;
    float* cb2 = (float*)p;                     p += 256 * 1024;
    float* hpf = (float*)p;                     p += 128 * 1024;
    float* hpr = (float*)p;                     p += 128 * 1024;
    u16* w1p   = (u16*)p;                       p += 512 * 1024;   // W1ih bf16 [1024][256]
    u16* w2p   = (u16*)p;                       p += 512 * 1024;   // W2ih bf16
    u16* wfp   = (u16*)p;                       p += 128 * 1024;   // Wih_f bf16 [512][128]
    u16* wrp   = (u16*)p;                       p += 128 * 1024;   // Wih_r bf16
    u16* wh1p  = (u16*)p;                       p += 512 * 1024;   // W1hh bf16
    u16* wh2p  = (u16*)p;                       p += 512 * 1024;   // W2hh bf16
    u16* whfp  = (u16*)p;                       p += 128 * 1024;   // Whh_f bf16
    u16* whrp  = (u16*)p;                       // Whh_r bf16

    const int CH1 = 32, n1 = 8;    // stage-1 chunking
    const int CH  = 16, n2 = 16;   // stage-2/3 chunking

    // one-time weight conversions (2 launches, 4 arrays each)
    prep_w4_kernel<<<2560, 256, 0, stream>>>(
        W1ih, w1p, 1024, W2ih, w2p, 1024, Wih_f, wfp, 256, Wih_r, wrp);
    prep_w4_kernel<<<2560, 256, 0, stream>>>(
        W1hh, wh1p, 1024, W2hh, wh2p, 1024, Whh_f, whfp, 256, Whh_r, whrp);

    // stage 1: bidirectional H=128 LSTM -> X1 (raw concat)
    for (int i = 0; i <= n1; ++i) {
        int gon = (i < n1), ron = (i >= 1);
        float* wf = (i & 1) ? G3[0] : G2[0];
        float* wr = (i & 1) ? G3[1] : G2[1];
        const float* rf = ((i - 1) & 1) ? G3[0] : G2[0];
        const float* rr_ = ((i - 1) & 1) ? G3[1] : G2[1];
        fused1_kernel<<<2112, 256, 0, stream>>>(
            embed, wfp, b_f, wrp, b_r, wf, wr, CH1 * i, 256 - CH1 * (i + 1), gon,
            rf, rr_, whfp, whrp, cbf, cbr, hpf, hpr, X1, CH1 * (i - 1), CH1 * i, ron);
    }

    // ln1 + bf16 hi/lo split, in place over X1
    prep_x1_kernel<<<16384, 256, 0, stream>>>(X1, ln1g, ln1b);
    const u16* X1p = (const u16*)X1;

    // stages 2+3, deep pipeline
    xg2_kernel<<<dim3(4, CH * 4), 256, 0, stream>>>(X1p, w1p, b1, G2[0], 0);
    for (int i = 0; i <= n2 + 1; ++i) {
        int s2on = (i < n2), s3on = (i >= 2);
        int g2on = (i + 1 < n2), g3on = (i >= 1 && i <= n2);
        fused2_kernel<<<1024, 256, 0, stream>>>(
            G2[i & 1], wh1p, cb1, hb1, R[i & 1], CH * i, CH * (i + 1), s2on,
            G3[(i - 2) & 1], wh2p, cb2, hb2, (float*)d_out, lastidx, bng, bnb,
            CH * (i - 2), CH * (i - 1), s3on,
            X1p, w1p, b1, G2[(i + 1) & 1], CH * (i + 1), g2on,
            R[(i - 1) & 1], ln2g, ln2b, w2p, b2, G3[(i - 1) & 1], CH * (i - 1), g3on);
    }
}